// Round 8
// baseline (268.670 us; speedup 1.0000x reference)
//
#include <hip/hip_runtime.h>
#include <hip/hip_bf16.h>

#define B_ 2
#define S_ 1024
#define F_ 1024
#define H_ 8
#define D_ 64
#define R_ 2
#define BH (B_*H_)
#define NC 64
#define CL (S_/NC)   // 16

// combined projection layout: [M, NPROJ] fp32
#define QOFF 0
#define KOFF 512
#define VOFF 1536
#define BOFF 2560
#define NPROJ 2624   // 41 * 64

typedef __bf16 bf16x8 __attribute__((ext_vector_type(8)));
typedef unsigned short ushort8 __attribute__((ext_vector_type(8)));
typedef float f32x4 __attribute__((ext_vector_type(4)));

__device__ __forceinline__ unsigned short f2bf(float f) {
    unsigned u = __builtin_bit_cast(unsigned, f);
    unsigned r = u + 0x7FFFu + ((u >> 16) & 1u);
    return (unsigned short)(r >> 16);
}

__device__ __forceinline__ void gload_lds16(const void* g, void* l) {
    __builtin_amdgcn_global_load_lds(
        (const __attribute__((address_space(1))) void*)g,
        (__attribute__((address_space(3))) void*)l, 16, 0, 0);
}

// S0[c] lives in Ac slot (c&~3)|((c+3)&3):
//   S0[4g]->4g+3 (Asup, dead after combine16), S0[4g+1]->4g,
//   S0[4g+2]->4g+1, S0[4g+3]->4g+2 (fixup stages before overwrite).
__device__ __forceinline__ int s0slot(int c) { return (c & ~3) | ((c + 3) & 3); }

// ------------------------------------------------------------------
// Mask format sniffer + normalize to float 0/1.
// ------------------------------------------------------------------
__global__ void k_mask_prep(const void* __restrict__ mraw, float* __restrict__ maskf, int n) {
    __shared__ int fmt; // 0=int32, 1=byte, 2=float32
    int t = threadIdx.x;
    if (t == 0) fmt = 0;
    __syncthreads();
    const unsigned int* u32 = (const unsigned int*)mraw;
    for (int g = t; g < n / 4; g += blockDim.x) {
        unsigned int v = u32[g];
        if (v == 0x3F800000u) atomicMax(&fmt, 2);
        else if (v != 0u && v != 1u) atomicMax(&fmt, 1);
    }
    __syncthreads();
    int f = fmt;
    const unsigned char* u8 = (const unsigned char*)mraw;
    const float* f32 = (const float*)mraw;
    for (int i = t; i < n; i += blockDim.x) {
        float mv;
        if (f == 1)      mv = u8[i] ? 1.f : 0.f;
        else if (f == 2) mv = (f32[i] != 0.f) ? 1.f : 0.f;
        else             mv = (u32[i] != 0u) ? 1.f : 0.f;
        maskf[i] = mv;
    }
}

// ------------------------------------------------------------------
// fp32 -> bf16 elementwise (n % 4 == 0)
// ------------------------------------------------------------------
__global__ void k_f32_to_bf16(const float* __restrict__ s, unsigned short* __restrict__ d, int n) {
    int i = (blockIdx.x * blockDim.x + threadIdx.x) * 4;
    if (i < n) {
        float4 v = *(const float4*)&s[i];
        d[i + 0] = f2bf(v.x); d[i + 1] = f2bf(v.y);
        d[i + 2] = f2bf(v.z); d[i + 3] = f2bf(v.w);
    }
}

// ------------------------------------------------------------------
// Transpose [K,N] f32 -> [N,K] bf16. 32x32 tiles, 256 threads.
// ------------------------------------------------------------------
__global__ __launch_bounds__(256) void k_transpose_to_bf16(
    const float* __restrict__ src, unsigned short* __restrict__ dst, int K, int N)
{
    __shared__ float tile[32][33];
    int bx = blockIdx.x, by = blockIdx.y;
    int tx = threadIdx.x & 31, ty = threadIdx.x >> 5;
#pragma unroll
    for (int i = 0; i < 32; i += 8)
        tile[ty + i][tx] = src[(size_t)(by * 32 + ty + i) * N + bx * 32 + tx];
    __syncthreads();
#pragma unroll
    for (int i = 0; i < 32; i += 8)
        dst[(size_t)(bx * 32 + ty + i) * K + by * 32 + tx] = f2bf(tile[tx][ty + i]);
}

// ------------------------------------------------------------------
// Wb [1024,16] f32 -> rows BOFF..BOFF+63 of wt as [64,1024] bf16.
// ------------------------------------------------------------------
__global__ void k_wb_pad(const float* __restrict__ Wb, unsigned short* __restrict__ dst) {
    int row = blockIdx.x;
    int c0 = threadIdx.x * 4;
#pragma unroll
    for (int c = c0; c < c0 + 4; ++c)
        dst[(size_t)row * 1024 + c] = (row < 16) ? f2bf(Wb[(size_t)c * 16 + row]) : (unsigned short)0;
}

// ------------------------------------------------------------------
// bf16 MFMA GEMM: C[M,N] = A[M,K] @ B[K,N] (+bias). Tile 128x64, BK=64.
// ------------------------------------------------------------------
__global__ __launch_bounds__(256) void k_gemm_bf16(
    const unsigned short* __restrict__ A, const unsigned short* __restrict__ Bt,
    const float* __restrict__ bias, float* __restrict__ C,
    int M, int N, int K)
{
    constexpr int BM = 128, BN = 64, BK = 64;
    __shared__ unsigned short sA[BM * BK];
    __shared__ unsigned short sB[BN * BK];
    int t = threadIdx.x;
    int w = t >> 6, l = t & 63;
    int rowb = blockIdx.y * BM, colb = blockIdx.x * BN;
    int wr = w >> 1, wc = w & 1;
    int fr = l & 15, kgrp = l >> 4;

    f32x4 acc[4][2];
#pragma unroll
    for (int m = 0; m < 4; ++m)
#pragma unroll
        for (int n = 0; n < 2; ++n) acc[m][n] = (f32x4){0.f, 0.f, 0.f, 0.f};

    int lrow_off = l >> 3;
    int kg_phys = l & 7;

    for (int k0 = 0; k0 < K; k0 += BK) {
        __syncthreads();
#pragma unroll
        for (int is = 0; is < 4; ++is) {
            int r0 = (w * 4 + is) * 8;
            int row = r0 + lrow_off;
            int kg_log = kg_phys ^ (row & 7);
            gload_lds16(A + (size_t)(rowb + row) * K + k0 + kg_log * 8, &sA[r0 * BK]);
        }
#pragma unroll
        for (int is = 0; is < 2; ++is) {
            int r0 = (w * 2 + is) * 8;
            int row = r0 + lrow_off;
            int kg_log = kg_phys ^ (row & 7);
            gload_lds16(Bt + (size_t)(colb + row) * K + k0 + kg_log * 8, &sB[r0 * BK]);
        }
        asm volatile("s_waitcnt vmcnt(0)" ::: "memory");
        __syncthreads();

#pragma unroll
        for (int kk = 0; kk < BK; kk += 32) {
            int kg = (kk >> 3) + kgrp;
            bf16x8 af[4], bfv[2];
#pragma unroll
            for (int m = 0; m < 4; ++m) {
                int row = wr * 64 + m * 16 + fr;
                ushort8 raw = *(const ushort8*)&sA[row * BK + (kg ^ (row & 7)) * 8];
                af[m] = __builtin_bit_cast(bf16x8, raw);
            }
#pragma unroll
            for (int n = 0; n < 2; ++n) {
                int row = wc * 32 + n * 16 + fr;
                ushort8 raw = *(const ushort8*)&sB[row * BK + (kg ^ (row & 7)) * 8];
                bfv[n] = __builtin_bit_cast(bf16x8, raw);
            }
#pragma unroll
            for (int m = 0; m < 4; ++m)
#pragma unroll
                for (int n = 0; n < 2; ++n)
                    acc[m][n] = __builtin_amdgcn_mfma_f32_16x16x32_bf16(af[m], bfv[n], acc[m][n], 0, 0, 0);
        }
    }

#pragma unroll
    for (int m = 0; m < 4; ++m)
#pragma unroll
        for (int n = 0; n < 2; ++n) {
            int grow0 = rowb + wr * 64 + m * 16 + kgrp * 4;
            int gcol  = colb + wc * 32 + n * 16 + fr;
            float bv = bias ? bias[gcol] : 0.f;
#pragma unroll
            for (int r = 0; r < 4; ++r)
                C[(size_t)(grow0 + r) * N + gcol] = acc[m][n][r] + bv;
        }
}

// ------------------------------------------------------------------
// silu then L2-normalize per group of 64 with strided row layout.
// ------------------------------------------------------------------
__global__ void k_silu_norm(float* __restrict__ buf, int ngroups,
                            int gshift, int gmask, int rowstride, int coloff) {
    int w = threadIdx.x >> 6;
    int l = threadIdx.x & 63;
    int g = blockIdx.x * 4 + w;
    if (g >= ngroups) return;
    size_t idx = (size_t)(g >> gshift) * rowstride + coloff + ((g & gmask) << 6) + l;
    float x = buf[idx];
    float s = x / (1.f + expf(-x));
    float ss = s * s;
#pragma unroll
    for (int m = 1; m < 64; m <<= 1) ss += __shfl_xor(ss, m);
    float nrm = sqrtf(ss) + 1e-6f;
    buf[idx] = s / nrm;
}

// ------------------------------------------------------------------
// Phase 1: per (bh, chunk) transfer operators (A_c, B_c). CL=16.
// ------------------------------------------------------------------
__global__ __launch_bounds__(128) void k_chunk_transfer(
    const float* __restrict__ proj, const float* __restrict__ maskf,
    float* __restrict__ Ac, float* __restrict__ Bc)
{
    int c = blockIdx.x;
    int bh = blockIdx.y;
    int b = bh >> 3, h = bh & 7;
    int t = threadIdx.x;
    int w = t >> 6, lane = t & 63;
    __shared__ float sK[CL][128];   // 8 KB
    __shared__ float4 sScal[CL];

    size_t tokbase = (size_t)(b * S_ + c * CL);
#pragma unroll
    for (int it = 0; it < (CL * 32) / 128; ++it) {
        int f = it * 128 + t;
        int tok = f >> 5, wi = f & 31;
        gload_lds16(&proj[(tokbase + tok) * NPROJ + KOFF + h * 128 + wi * 4],
                    &sK[0][0] + (size_t)(it * 128 + w * 64) * 4);
    }
    if (t < CL) {
        float r0 = proj[(tokbase + t) * NPROJ + BOFF + h * 2 + 0];
        float r1 = proj[(tokbase + t) * NPROJ + BOFF + h * 2 + 1];
        float ms = 1.f - maskf[tokbase + t];
        sScal[t] = make_float4(1.f / (1.f + expf(-r0)), 1.f / (1.f + expf(-r1)), ms, 0.f);
    }
    asm volatile("s_waitcnt vmcnt(0)" ::: "memory");
    __syncthreads();

    float St[64];
#pragma unroll
    for (int j = 0; j < 64; ++j) St[j] = (w == 0 && j == lane) ? 1.f : 0.f;

    const float* vbase = &proj[tokbase * NPROJ + VOFF + h * 128];
    float v0 = vbase[lane], v1 = vbase[64 + lane];

    for (int sl = 0; sl < CL; ++sl) {
        float vc0 = v0, vc1 = v1;
        if (sl + 1 < CL) {
            const float* nb = vbase + (size_t)(sl + 1) * NPROJ;
            v0 = nb[lane]; v1 = nb[64 + lane];
        }
        float4 sc = sScal[sl];
        if (sc.z == 0.f) {
#pragma unroll
            for (int j = 0; j < 64; ++j) St[j] = 0.f;
        }
#pragma unroll
        for (int r = 0; r < 2; ++r) {
            float br = (r == 0) ? sc.x : sc.y;
            float vi = (r == 0) ? vc0 : vc1;
            float4 kk[16];
#pragma unroll
            for (int j = 0; j < 16; ++j) kk[j] = *(const float4*)&sK[sl][r * 64 + j * 4];
            float u0 = 0.f, u1 = 0.f, u2 = 0.f, u3 = 0.f;
#pragma unroll
            for (int j = 0; j < 16; ++j) {
                u0 = fmaf(St[j * 4 + 0], kk[j].x, u0);
                u1 = fmaf(St[j * 4 + 1], kk[j].y, u1);
                u2 = fmaf(St[j * 4 + 2], kk[j].z, u2);
                u3 = fmaf(St[j * 4 + 3], kk[j].w, u3);
            }
            float u = (u0 + u1) + (u2 + u3);
            float coef = (w == 0) ? (-br * u) : (br * (vi - u));
#pragma unroll
            for (int j = 0; j < 16; ++j) {
                St[j * 4 + 0] = fmaf(coef, kk[j].x, St[j * 4 + 0]);
                St[j * 4 + 1] = fmaf(coef, kk[j].y, St[j * 4 + 1]);
                St[j * 4 + 2] = fmaf(coef, kk[j].z, St[j * 4 + 2]);
                St[j * 4 + 3] = fmaf(coef, kk[j].w, St[j * 4 + 3]);
            }
        }
    }
    float* dst = (w == 0 ? Ac : Bc) + ((size_t)bh * NC + c) * 4096 + (size_t)lane * 64;
#pragma unroll
    for (int j = 0; j < 16; ++j)
        *(float4*)&dst[j * 4] = make_float4(St[j * 4], St[j * 4 + 1], St[j * 4 + 2], St[j * 4 + 3]);
}

// ------------------------------------------------------------------
// Stage 4096 floats from global into padded [64][68] LDS (reg path).
// ------------------------------------------------------------------
__device__ __forceinline__ void stage_padded(const float* __restrict__ g, float* lds, int t) {
#pragma unroll
    for (int s = 0; s < 4; ++s) {
        int f = s * 256 + t;
        float4 v = *(const float4*)&g[(size_t)f * 4];
        int r = f >> 4, c = (f & 15) * 4;
        *(float4*)&lds[r * 68 + c] = v;
    }
}

// ------------------------------------------------------------------
// Pairwise merge of transfer ops, in place into the RIGHT slot:
//   Aout = Al*Ar ; Bout = Bl*Ar + Br.
// slots: left = p*stride+leftOff, right = p*stride+rightOff.
// Thread: row i = t>>2, 16 cols at j0 = (t&3)*16.
// ------------------------------------------------------------------
__global__ __launch_bounds__(256) void k_merge(
    float* __restrict__ Ac, float* __restrict__ Bc,
    int leftOff, int rightOff, int stride)
{
    int p = blockIdx.x, bh = blockIdx.y;
    size_t base = (size_t)bh * NC * 4096;
    size_t li = base + (size_t)(p * stride + leftOff) * 4096;
    size_t ri = base + (size_t)(p * stride + rightOff) * 4096;
    int t = threadIdx.x;
    int i = t >> 2, j0 = (t & 3) * 16;
    __shared__ float sAl[64 * 68];
    __shared__ float sBl[64 * 68];
    __shared__ float sAr[4096];

#pragma unroll
    for (int s = 0; s < 4; ++s)
        gload_lds16(Ac + ri + (size_t)(s * 256 + t) * 4, &sAr[(size_t)(s * 256 + (t & 192)) * 4]);
    stage_padded(Ac + li, sAl, t);
    stage_padded(Bc + li, sBl, t);
    float4 aB[4], aA[4];
#pragma unroll
    for (int q = 0; q < 4; ++q) {
        aB[q] = *(const float4*)&Bc[ri + (size_t)i * 64 + j0 + q * 4];
        aA[q] = make_float4(0.f, 0.f, 0.f, 0.f);
    }
    asm volatile("s_waitcnt vmcnt(0)" ::: "memory");
    __syncthreads();

#pragma unroll 4
    for (int pp = 0; pp < 64; ++pp) {
        float la = sAl[i * 68 + pp];
        float lb = sBl[i * 68 + pp];
#pragma unroll
        for (int q = 0; q < 4; ++q) {
            float4 ar = *(const float4*)&sAr[pp * 64 + j0 + q * 4];
            aA[q].x = fmaf(la, ar.x, aA[q].x); aA[q].y = fmaf(la, ar.y, aA[q].y);
            aA[q].z = fmaf(la, ar.z, aA[q].z); aA[q].w = fmaf(la, ar.w, aA[q].w);
            aB[q].x = fmaf(lb, ar.x, aB[q].x); aB[q].y = fmaf(lb, ar.y, aB[q].y);
            aB[q].z = fmaf(lb, ar.z, aB[q].z); aB[q].w = fmaf(lb, ar.w, aB[q].w);
        }
    }
#pragma unroll
    for (int q = 0; q < 4; ++q) {
        *(float4*)&Ac[ri + (size_t)i * 64 + j0 + q * 4] = aA[q];
        *(float4*)&Bc[ri + (size_t)i * 64 + j0 + q * 4] = aB[q];
    }
}

// ------------------------------------------------------------------
// Serial combine over 16 supers; ONE block per bh (no cross-block
// races on aliased S0). State rows in registers; old-row values via
// __shfl within the 4-lane row group; A double-buffered via async
// global_load_lds. Writes S0[4g] into Ac slot 4g+3 (= consumed Asup).
// ------------------------------------------------------------------
__global__ __launch_bounds__(256) void k_combine16(
    float* __restrict__ Ac, const float* __restrict__ Bc,
    const float* __restrict__ carry, float* __restrict__ carry_out)
{
    int bh = blockIdx.x;
    int t = threadIdx.x;
    int i = t >> 2, j0 = (t & 3) * 16;
    int rbase = t & ~3;            // lane group base (same row)
    __shared__ float sA[2][4096];  // 32 KB double buffer

    size_t base = (size_t)bh * NC * 4096;
    // prologue: stage Asup[0] (slot 3), load Bsup[0], init acc = carry
#pragma unroll
    for (int s = 0; s < 4; ++s)
        gload_lds16(Ac + base + (size_t)3 * 4096 + (size_t)(s * 256 + t) * 4,
                    &sA[0][(size_t)(s * 256 + (t & 192)) * 4]);
    float4 rB[4], acc[4];
#pragma unroll
    for (int q = 0; q < 4; ++q) {
        rB[q]  = *(const float4*)&Bc[base + (size_t)3 * 4096 + (size_t)i * 64 + j0 + q * 4];
        acc[q] = *(const float4*)&carry[(size_t)bh * 4096 + (size_t)i * 64 + j0 + q * 4];
    }
    asm volatile("s_waitcnt vmcnt(0)" ::: "memory");
    __syncthreads();

    for (int g = 0; g < 16; ++g) {
        int cur = g & 1;
        size_t slot = base + (size_t)(4 * g + 3) * 4096;
        // S0[4g] -> Ac slot 4g+3 (already staged in LDS)
#pragma unroll
        for (int q = 0; q < 4; ++q)
            *(float4*)&Ac[slot + (size_t)i * 64 + j0 + q * 4] = acc[q];
        float4 rBn[4];
        if (g + 1 < 16) {
            size_t nslot = base + (size_t)(4 * g + 7) * 4096;
#pragma unroll
            for (int s = 0; s < 4; ++s)
                gload_lds16(Ac + nslot + (size_t)(s * 256 + t) * 4,
                            &sA[cur ^ 1][(size_t)(s * 256 + (t & 192)) * 4]);
#pragma unroll
            for (int q = 0; q < 4; ++q)
                rBn[q] = *(const float4*)&Bc[nslot + (size_t)i * 64 + j0 + q * 4];
        }
        // old = acc; acc = Bsup; acc += S_old * Asup
        float old[16];
#pragma unroll
        for (int q = 0; q < 4; ++q) {
            old[q * 4 + 0] = acc[q].x; old[q * 4 + 1] = acc[q].y;
            old[q * 4 + 2] = acc[q].z; old[q * 4 + 3] = acc[q].w;
            acc[q] = rB[q];
        }
#pragma unroll
        for (int pg = 0; pg < 4; ++pg) {
#pragma unroll
            for (int pi = 0; pi < 16; ++pi) {
                float s = __shfl(old[pi], rbase + pg);
                int pp = pg * 16 + pi;
#pragma unroll
                for (int q = 0; q < 4; ++q) {
                    float4 ar = *(const float4*)&sA[cur][pp * 64 + j0 + q * 4];
                    acc[q].x = fmaf(s, ar.x, acc[q].x);
                    acc[q].y = fmaf(s, ar.y, acc[q].y);
                    acc[q].z = fmaf(s, ar.z, acc[q].z);
                    acc[q].w = fmaf(s, ar.w, acc[q].w);
                }
            }
        }
#pragma unroll
        for (int q = 0; q < 4; ++q) rB[q] = rBn[q];
        asm volatile("s_waitcnt vmcnt(0)" ::: "memory");  // next A staged
        __syncthreads();                                   // reads of sA[cur] done
    }
#pragma unroll
    for (int q = 0; q < 4; ++q)
        *(float4*)&carry_out[(size_t)bh * 4096 + (size_t)i * 64 + j0 + q * 4] = acc[q];
}

// ------------------------------------------------------------------
// Fixup: per (super g, bh) expand S0 to all chunk starts:
//   S0[4g+1] = Ssup*A[4g]      + B[4g]        -> Ac slot 4g
//   S0[4g+2] = Ssup*Apair[2g]  + Bpair[2g]    -> Ac slot 4g+1
//   S0[4g+3] = S0[4g+2]*A[4g+2]+ B[4g+2]      -> Ac slot 4g+2
// ------------------------------------------------------------------
__global__ __launch_bounds__(256) void k_fixup(
    float* __restrict__ Ac, const float* __restrict__ Bc)
{
    int g = blockIdx.x, bh = blockIdx.y;
    int t = threadIdx.x;
    int i = t >> 2, j0 = (t & 3) * 16;
    size_t base = (size_t)bh * NC * 4096;
    size_t s0 = base + (size_t)(4 * g + 0) * 4096;   // A[4g] / out S0[4g+1]
    size_t s1 = base + (size_t)(4 * g + 1) * 4096;   // Apair[2g] / out S0[4g+2]
    size_t s2 = base + (size_t)(4 * g + 2) * 4096;   // A[4g+2] / out S0[4g+3]
    size_t s3 = base + (size_t)(4 * g + 3) * 4096;   // Ssup = S0[4g]
    __shared__ float sS[64 * 68];
    __shared__ float sA1[4096];
    __shared__ float sA2[4096];

#pragma unroll
    for (int s = 0; s < 4; ++s) {
        gload_lds16(Ac + s0 + (size_t)(s * 256 + t) * 4, &sA1[(size_t)(s * 256 + (t & 192)) * 4]);
        gload_lds16(Ac + s1 + (size_t)(s * 256 + t) * 4, &sA2[(size_t)(s * 256 + (t & 192)) * 4]);
    }
    stage_padded(Ac + s3, sS, t);
    float4 acc1[4], acc2[4];
#pragma unroll
    for (int q = 0; q < 4; ++q) {
        acc1[q] = *(const float4*)&Bc[s0 + (size_t)i * 64 + j0 + q * 4];
        acc2[q] = *(const float4*)&Bc[s1 + (size_t)i * 64 + j0 + q * 4];
    }
    asm volatile("s_waitcnt vmcnt(0)" ::: "memory");
    __syncthreads();

#pragma unroll 4
    for (int pp = 0; pp < 64; ++pp) {
        float s = sS[i * 68 + pp];
#pragma unroll
        for (int q = 0; q < 4; ++q) {
            float4 a1 = *(const float4*)&sA1[pp * 64 + j0 + q * 4];
            float4 a2 = *(const float4*)&sA2[pp * 64 + j0 + q * 4];
            acc1[q].x = fmaf(s, a1.x, acc1[q].x); acc1[q].y = fmaf(s, a1.y, acc1[q].y);
            acc1[q].z = fmaf(s, a1.z, acc1[q].z); acc1[q].w = fmaf(s, a1.w, acc1[q].w);
            acc2[q].x = fmaf(s, a2.x, acc2[q].x); acc2[q].y = fmaf(s, a2.y, acc2[q].y);
            acc2[q].z = fmaf(s, a2.z, acc2[q].z); acc2[q].w = fmaf(s, a2.w, acc2[q].w);
        }
    }
    __syncthreads();   // all reads of sS/sA1 done before overwrite
    // restage: sA1 <- A[4g+2]; sS <- acc2 (= S0[4g+2])
#pragma unroll
    for (int s = 0; s < 4; ++s)
        gload_lds16(Ac + s2 + (size_t)(s * 256 + t) * 4, &sA1[(size_t)(s * 256 + (t & 192)) * 4]);
#pragma unroll
    for (int q = 0; q < 4; ++q)
        *(float4*)&sS[i * 68 + j0 + q * 4] = acc2[q];
    float4 acc3[4];
#pragma unroll
    for (int q = 0; q < 4; ++q)
        acc3[q] = *(const float4*)&Bc[s2 + (size_t)i * 64 + j0 + q * 4];
    // write S0[4g+1] and S0[4g+2] (slots s0, s1 — staged copies in LDS/regs)
#pragma unroll
    for (int q = 0; q < 4; ++q) {
        *(float4*)&Ac[s0 + (size_t)i * 64 + j0 + q * 4] = acc1[q];
        *(float4*)&Ac[s1 + (size_t)i * 64 + j0 + q * 4] = acc2[q];
    }
    asm volatile("s_waitcnt vmcnt(0)" ::: "memory");
    __syncthreads();

#pragma unroll 4
    for (int pp = 0; pp < 64; ++pp) {
        float s = sS[i * 68 + pp];
#pragma unroll
        for (int q = 0; q < 4; ++q) {
            float4 a3 = *(const float4*)&sA1[pp * 64 + j0 + q * 4];
            acc3[q].x = fmaf(s, a3.x, acc3[q].x); acc3[q].y = fmaf(s, a3.y, acc3[q].y);
            acc3[q].z = fmaf(s, a3.z, acc3[q].z); acc3[q].w = fmaf(s, a3.w, acc3[q].w);
        }
    }
#pragma unroll
    for (int q = 0; q < 4; ++q)
        *(float4*)&Ac[s2 + (size_t)i * 64 + j0 + q * 4] = acc3[q];
}

// ------------------------------------------------------------------
// Phase 3: rerun recurrence from S0 (aliased in Ac), emit x = St q.
// ------------------------------------------------------------------
__global__ __launch_bounds__(64) void k_emit_x(
    float* __restrict__ proj, const float* __restrict__ maskf,
    const float* __restrict__ S0ac)
{
    int c = blockIdx.x;
    int bh = blockIdx.y;
    int b = bh >> 3, h = bh & 7;
    int lane = threadIdx.x;
    __shared__ float sK[CL][128];
    __shared__ float sQ[CL][64];
    __shared__ float4 sScal[CL];

    size_t tokbase = (size_t)(b * S_ + c * CL);
#pragma unroll
    for (int it = 0; it < (CL * 32) / 64; ++it) {
        int f = it * 64 + lane;
        int tok = f >> 5, wi = f & 31;
        gload_lds16(&proj[(tokbase + tok) * NPROJ + KOFF + h * 128 + wi * 4],
                    &sK[0][0] + (size_t)(it * 64) * 4);
    }
#pragma unroll
    for (int it = 0; it < (CL * 16) / 64; ++it) {
        int f = it * 64 + lane;
        int tok = f >> 4, wi = f & 15;
        gload_lds16(&proj[(tokbase + tok) * NPROJ + QOFF + h * 64 + wi * 4],
                    &sQ[0][0] + (size_t)(it * 64) * 4);
    }
    if (lane < CL) {
        float r0 = proj[(tokbase + lane) * NPROJ + BOFF + h * 2 + 0];
        float r1 = proj[(tokbase + lane) * NPROJ + BOFF + h * 2 + 1];
        float ms = 1.f - maskf[tokbase + lane];
        sScal[lane] = make_float4(1.f / (1.f + expf(-r0)), 1.f / (1.f + expf(-r1)), ms, 0.f);
    }
    asm volatile("s_waitcnt vmcnt(0)" ::: "memory");
    __syncthreads();

    float St[64];
    const float* sp = S0ac + ((size_t)bh * NC + s0slot(c)) * 4096 + (size_t)lane * 64;
#pragma unroll
    for (int j = 0; j < 16; ++j) {
        float4 s4 = *(const float4*)&sp[j * 4];
        St[j * 4] = s4.x; St[j * 4 + 1] = s4.y; St[j * 4 + 2] = s4.z; St[j * 4 + 3] = s4.w;
    }

    const float* vbase = &proj[tokbase * NPROJ + VOFF + h * 128];
    float v0 = vbase[lane], v1 = vbase[64 + lane];

    for (int sl = 0; sl < CL; ++sl) {
        float vc0 = v0, vc1 = v1;
        if (sl + 1 < CL) {
            const float* nb = vbase + (size_t)(sl + 1) * NPROJ;
            v0 = nb[lane]; v1 = nb[64 + lane];
        }
        float4 sc = sScal[sl];
        if (sc.z == 0.f) {
#pragma unroll
            for (int j = 0; j < 64; ++j) St[j] = 0.f;
        }
#pragma unroll
        for (int r = 0; r < 2; ++r) {
            float br = (r == 0) ? sc.x : sc.y;
            float vi = (r == 0) ? vc0 : vc1;
            float4 kk[16];
#pragma unroll
            for (int j = 0; j < 16; ++j) kk[j] = *(const float4*)&sK[sl][r * 64 + j * 4];
            float u0 = 0.f, u1 = 0.f, u2 = 0.f, u3 = 0.f;
#pragma unroll
            for (int j = 0; j < 16; ++j) {
                u0 = fmaf(St[j * 4 + 0], kk[j].x, u0);
                u1 = fmaf(St[j * 4 + 1], kk[j].y, u1);
                u2 = fmaf(St[j * 4 + 2], kk[j].z, u2);
                u3 = fmaf(St[j * 4 + 3], kk[j].w, u3);
            }
            float u = (u0 + u1) + (u2 + u3);
            float coef = br * (vi - u);
#pragma unroll
            for (int j = 0; j < 16; ++j) {
                St[j * 4 + 0] = fmaf(coef, kk[j].x, St[j * 4 + 0]);
                St[j * 4 + 1] = fmaf(coef, kk[j].y, St[j * 4 + 1]);
                St[j * 4 + 2] = fmaf(coef, kk[j].z, St[j * 4 + 2]);
                St[j * 4 + 3] = fmaf(coef, kk[j].w, St[j * 4 + 3]);
            }
        }
        float x0 = 0.f, x1 = 0.f, x2 = 0.f, x3 = 0.f;
#pragma unroll
        for (int j = 0; j < 16; ++j) {
            float4 qq = *(const float4*)&sQ[sl][j * 4];
            x0 = fmaf(St[j * 4 + 0], qq.x, x0);
            x1 = fmaf(St[j * 4 + 1], qq.y, x1);
            x2 = fmaf(St[j * 4 + 2], qq.z, x2);
            x3 = fmaf(St[j * 4 + 3], qq.w, x3);
        }
        float xv = (x0 + x1) + (x2 + x3);
        proj[(tokbase + sl) * NPROJ + QOFF + h * 64 + lane] = xv;
    }
}

// ------------------------------------------------------------------
// RMS norm over x = proj cols 0..511, * rms_scale, emit compact bf16.
// ------------------------------------------------------------------
__global__ void k_rms_bf16(const float* __restrict__ proj, const float* __restrict__ scale,
                           unsigned short* __restrict__ xo) {
    int w = threadIdx.x >> 6;
    int l = threadIdx.x & 63;
    size_t row = (size_t)blockIdx.x * 4 + w;
    float4 v0 = *(const float4*)&proj[row * NPROJ + l * 8];
    float4 v1 = *(const float4*)&proj[row * NPROJ + l * 8 + 4];
    float ss = v0.x * v0.x + v0.y * v0.y + v0.z * v0.z + v0.w * v0.w
             + v1.x * v1.x + v1.y * v1.y + v1.z * v1.z + v1.w * v1.w;
#pragma unroll
    for (int m = 1; m < 64; m <<= 1) ss += __shfl_xor(ss, m);
    float sc = rsqrtf(ss * (1.f / 512.f) + 1e-6f);
    float4 s0 = *(const float4*)&scale[l * 8];
    float4 s1 = *(const float4*)&scale[l * 8 + 4];
    ushort8 o;
    o[0] = f2bf(v0.x * sc * s0.x); o[1] = f2bf(v0.y * sc * s0.y);
    o[2] = f2bf(v0.z * sc * s0.z); o[3] = f2bf(v0.w * sc * s0.w);
    o[4] = f2bf(v1.x * sc * s1.x); o[5] = f2bf(v1.y * sc * s1.y);
    o[6] = f2bf(v1.z * sc * s1.z); o[7] = f2bf(v1.w * sc * s1.w);
    *(ushort8*)&xo[row * 512 + l * 8] = o;
}

// ------------------------------------------------------------------
extern "C" void kernel_launch(void* const* d_in, const int* in_sizes, int n_in,
                              void* d_out, int out_size, void* d_ws, size_t ws_size,
                              hipStream_t stream) {
    const float* inputs    = (const float*)d_in[0];
    const void*  mask      = d_in[1];
    const float* carry     = (const float*)d_in[2];
    const float* Wq        = (const float*)d_in[3];
    const float* Wk        = (const float*)d_in[4];
    const float* Wv        = (const float*)d_in[5];
    const float* Wb        = (const float*)d_in[6];
    const float* rms_scale = (const float*)d_in[7];
    const float* Wo        = (const float*)d_in[8];
    const float* bo        = (const float*)d_in[9];

    float* out_carry = (float*)d_out;
    float* out_y     = (float*)d_out + (size_t)B_ * H_ * D_ * D_;

    const int M = B_ * S_;  // 2048
    float* ws = (float*)d_ws;
    size_t o = 0;
    float* proj = ws + o; o += (size_t)M * NPROJ;
    float* mf   = ws + o; o += (size_t)M;
    float* Ac   = ws + o; o += (size_t)BH * NC * 4096;
    float* Bc   = ws + o; o += (size_t)BH * NC * 4096;
    unsigned short* wt = (unsigned short*)(ws + o); o += (size_t)NPROJ * 512;
    // overlays (lifetimes disjoint):
    unsigned short* inb = (unsigned short*)Bc;   // bf16 inputs, dead before phase 1 writes Bc
    unsigned short* xbf = (unsigned short*)Ac;   // rms output; Ac/S0 dead after emit_x

    k_mask_prep<<<1, 256, 0, stream>>>(mask, mf, M);
    k_f32_to_bf16<<<(M * 1024) / 1024, 256, 0, stream>>>(inputs, inb, M * 1024);

    // pack W^T = [Wq^T | Wk^T | Wv^T | Wb^T(pad to 64)] as [NPROJ,1024] bf16
    k_transpose_to_bf16<<<dim3(512 / 32, 1024 / 32), 256, 0, stream>>>(Wq, wt + (size_t)QOFF * 1024, 1024, 512);
    k_transpose_to_bf16<<<dim3(1024 / 32, 1024 / 32), 256, 0, stream>>>(Wk, wt + (size_t)KOFF * 1024, 1024, 1024);
    k_transpose_to_bf16<<<dim3(1024 / 32, 1024 / 32), 256, 0, stream>>>(Wv, wt + (size_t)VOFF * 1024, 1024, 1024);
    k_wb_pad<<<64, 256, 0, stream>>>(Wb, wt + (size_t)BOFF * 1024);

    // proj = inputs @ [Wq|Wk|Wv|Wb]
    k_gemm_bf16<<<dim3(NPROJ / 64, M / 128), 256, 0, stream>>>(inb, wt, nullptr, proj, M, NPROJ, 1024);

    // silu+L2norm on q (8 groups/row) and k (16 groups/row)
    k_silu_norm<<<(M * 8) / 4, 256, 0, stream>>>(proj, M * 8, 3, 7, NPROJ, QOFF);
    k_silu_norm<<<(M * 16) / 4, 256, 0, stream>>>(proj, M * 16, 4, 15, NPROJ, KOFF);

    // scan: per-chunk ops -> hierarchical combine -> fixup -> emit
    k_chunk_transfer<<<dim3(NC, BH), 128, 0, stream>>>(proj, mf, Ac, Bc);
    k_merge<<<dim3(NC / 2, BH), 256, 0, stream>>>(Ac, Bc, 0, 1, 2);   // 64 -> 32 pairs
    k_merge<<<dim3(NC / 4, BH), 256, 0, stream>>>(Ac, Bc, 1, 3, 4);   // 32 -> 16 supers
    k_combine16<<<BH, 256, 0, stream>>>(Ac, Bc, carry, out_carry);
    k_fixup<<<dim3(NC / 4, BH), 256, 0, stream>>>(Ac, Bc);
    k_emit_x<<<dim3(NC, BH), 64, 0, stream>>>(proj, mf, Ac);

    k_rms_bf16<<<M / 4, 256, 0, stream>>>(proj, rms_scale, xbf);

    // y = x @ Wo + bo  (K=512, N=1024); reuse wt for Wo^T
    k_transpose_to_bf16<<<dim3(1024 / 32, 512 / 32), 256, 0, stream>>>(Wo, wt, 512, 1024);
    k_gemm_bf16<<<dim3(1024 / 64, M / 128), 256, 0, stream>>>(xbf, wt, bo, out_y, M, 1024, 512);
}

// Round 9
// 165.572 us; speedup vs baseline: 1.6227x; 1.6227x over previous
//
#include <hip/hip_runtime.h>
#include <hip/hip_bf16.h>

#define B_ 2
#define S_ 1024
#define F_ 1024
#define H_ 8
#define D_ 64
#define R_ 2
#define BH (B_*H_)
#define NC 16
#define CL (S_/NC)   // 64

// combined projection layout: [M, NPROJ] fp32
#define QOFF 0
#define KOFF 512
#define VOFF 1536
#define BOFF 2560
#define NPROJ 2624   // 41 * 64

typedef __bf16 bf16x8 __attribute__((ext_vector_type(8)));
typedef unsigned short ushort8 __attribute__((ext_vector_type(8)));
typedef float f32x4 __attribute__((ext_vector_type(4)));

__device__ __forceinline__ unsigned short f2bf(float f) {
    unsigned u = __builtin_bit_cast(unsigned, f);
    unsigned r = u + 0x7FFFu + ((u >> 16) & 1u);
    return (unsigned short)(r >> 16);
}

__device__ __forceinline__ void gload_lds16(const void* g, void* l) {
    __builtin_amdgcn_global_load_lds(
        (const __attribute__((address_space(1))) void*)g,
        (__attribute__((address_space(3))) void*)l, 16, 0, 0);
}

// DPP quad-perm lane swap (VALU pipe, ~6cy vs ~120cy DS-pipe shfl).
template<int CTRL>
__device__ __forceinline__ float dppf(float x) {
    return __builtin_bit_cast(float, __builtin_amdgcn_update_dpp(
        0, __builtin_bit_cast(int, x), CTRL, 0xF, 0xF, true));
}
// sum across each aligned 4-lane quad: 0xB1 = [1,0,3,2], 0x4E = [2,3,0,1]
__device__ __forceinline__ float qsum4(float x) {
    x += dppf<0xB1>(x);
    x += dppf<0x4E>(x);
    return x;
}

// ------------------------------------------------------------------
// Mask format sniffer + normalize to float 0/1.
// ------------------------------------------------------------------
__global__ void k_mask_prep(const void* __restrict__ mraw, float* __restrict__ maskf, int n) {
    __shared__ int fmt; // 0=int32, 1=byte, 2=float32
    int t = threadIdx.x;
    if (t == 0) fmt = 0;
    __syncthreads();
    const unsigned int* u32 = (const unsigned int*)mraw;
    for (int g = t; g < n / 4; g += blockDim.x) {
        unsigned int v = u32[g];
        if (v == 0x3F800000u) atomicMax(&fmt, 2);
        else if (v != 0u && v != 1u) atomicMax(&fmt, 1);
    }
    __syncthreads();
    int f = fmt;
    const unsigned char* u8 = (const unsigned char*)mraw;
    const float* f32 = (const float*)mraw;
    for (int i = t; i < n; i += blockDim.x) {
        float mv;
        if (f == 1)      mv = u8[i] ? 1.f : 0.f;
        else if (f == 2) mv = (f32[i] != 0.f) ? 1.f : 0.f;
        else             mv = (u32[i] != 0u) ? 1.f : 0.f;
        maskf[i] = mv;
    }
}

// ------------------------------------------------------------------
// fp32 -> bf16 elementwise (n % 4 == 0)
// ------------------------------------------------------------------
__global__ void k_f32_to_bf16(const float* __restrict__ s, unsigned short* __restrict__ d, int n) {
    int i = (blockIdx.x * blockDim.x + threadIdx.x) * 4;
    if (i < n) {
        float4 v = *(const float4*)&s[i];
        d[i + 0] = f2bf(v.x); d[i + 1] = f2bf(v.y);
        d[i + 2] = f2bf(v.z); d[i + 3] = f2bf(v.w);
    }
}

// ------------------------------------------------------------------
// Transpose [K,N] f32 -> [N,K] bf16. 32x32 tiles, 256 threads.
// ------------------------------------------------------------------
__global__ __launch_bounds__(256) void k_transpose_to_bf16(
    const float* __restrict__ src, unsigned short* __restrict__ dst, int K, int N)
{
    __shared__ float tile[32][33];
    int bx = blockIdx.x, by = blockIdx.y;
    int tx = threadIdx.x & 31, ty = threadIdx.x >> 5;
#pragma unroll
    for (int i = 0; i < 32; i += 8)
        tile[ty + i][tx] = src[(size_t)(by * 32 + ty + i) * N + bx * 32 + tx];
    __syncthreads();
#pragma unroll
    for (int i = 0; i < 32; i += 8)
        dst[(size_t)(bx * 32 + ty + i) * K + by * 32 + tx] = f2bf(tile[tx][ty + i]);
}

// ------------------------------------------------------------------
// Wb [1024,16] f32 -> rows BOFF..BOFF+63 of wt as [64,1024] bf16.
// ------------------------------------------------------------------
__global__ void k_wb_pad(const float* __restrict__ Wb, unsigned short* __restrict__ dst) {
    int row = blockIdx.x;
    int c0 = threadIdx.x * 4;
#pragma unroll
    for (int c = c0; c < c0 + 4; ++c)
        dst[(size_t)row * 1024 + c] = (row < 16) ? f2bf(Wb[(size_t)c * 16 + row]) : (unsigned short)0;
}

// ------------------------------------------------------------------
// bf16 MFMA GEMM: C[M,N] = A[M,K] @ B[K,N] (+bias). Tile 128x64, BK=64.
// ------------------------------------------------------------------
__global__ __launch_bounds__(256) void k_gemm_bf16(
    const unsigned short* __restrict__ A, const unsigned short* __restrict__ Bt,
    const float* __restrict__ bias, float* __restrict__ C,
    int M, int N, int K)
{
    constexpr int BM = 128, BN = 64, BK = 64;
    __shared__ unsigned short sA[BM * BK];
    __shared__ unsigned short sB[BN * BK];
    int t = threadIdx.x;
    int w = t >> 6, l = t & 63;
    int rowb = blockIdx.y * BM, colb = blockIdx.x * BN;
    int wr = w >> 1, wc = w & 1;
    int fr = l & 15, kgrp = l >> 4;

    f32x4 acc[4][2];
#pragma unroll
    for (int m = 0; m < 4; ++m)
#pragma unroll
        for (int n = 0; n < 2; ++n) acc[m][n] = (f32x4){0.f, 0.f, 0.f, 0.f};

    int lrow_off = l >> 3;
    int kg_phys = l & 7;

    for (int k0 = 0; k0 < K; k0 += BK) {
        __syncthreads();
#pragma unroll
        for (int is = 0; is < 4; ++is) {
            int r0 = (w * 4 + is) * 8;
            int row = r0 + lrow_off;
            int kg_log = kg_phys ^ (row & 7);
            gload_lds16(A + (size_t)(rowb + row) * K + k0 + kg_log * 8, &sA[r0 * BK]);
        }
#pragma unroll
        for (int is = 0; is < 2; ++is) {
            int r0 = (w * 2 + is) * 8;
            int row = r0 + lrow_off;
            int kg_log = kg_phys ^ (row & 7);
            gload_lds16(Bt + (size_t)(colb + row) * K + k0 + kg_log * 8, &sB[r0 * BK]);
        }
        asm volatile("s_waitcnt vmcnt(0)" ::: "memory");
        __syncthreads();

#pragma unroll
        for (int kk = 0; kk < BK; kk += 32) {
            int kg = (kk >> 3) + kgrp;
            bf16x8 af[4], bfv[2];
#pragma unroll
            for (int m = 0; m < 4; ++m) {
                int row = wr * 64 + m * 16 + fr;
                ushort8 raw = *(const ushort8*)&sA[row * BK + (kg ^ (row & 7)) * 8];
                af[m] = __builtin_bit_cast(bf16x8, raw);
            }
#pragma unroll
            for (int n = 0; n < 2; ++n) {
                int row = wc * 32 + n * 16 + fr;
                ushort8 raw = *(const ushort8*)&sB[row * BK + (kg ^ (row & 7)) * 8];
                bfv[n] = __builtin_bit_cast(bf16x8, raw);
            }
#pragma unroll
            for (int m = 0; m < 4; ++m)
#pragma unroll
                for (int n = 0; n < 2; ++n)
                    acc[m][n] = __builtin_amdgcn_mfma_f32_16x16x32_bf16(af[m], bfv[n], acc[m][n], 0, 0, 0);
        }
    }

#pragma unroll
    for (int m = 0; m < 4; ++m)
#pragma unroll
        for (int n = 0; n < 2; ++n) {
            int grow0 = rowb + wr * 64 + m * 16 + kgrp * 4;
            int gcol  = colb + wc * 32 + n * 16 + fr;
            float bv = bias ? bias[gcol] : 0.f;
#pragma unroll
            for (int r = 0; r < 4; ++r)
                C[(size_t)(grow0 + r) * N + gcol] = acc[m][n][r] + bv;
        }
}

// ------------------------------------------------------------------
// silu then L2-normalize per group of 64 with strided row layout.
// ------------------------------------------------------------------
__global__ void k_silu_norm(float* __restrict__ buf, int ngroups,
                            int gshift, int gmask, int rowstride, int coloff) {
    int w = threadIdx.x >> 6;
    int l = threadIdx.x & 63;
    int g = blockIdx.x * 4 + w;
    if (g >= ngroups) return;
    size_t idx = (size_t)(g >> gshift) * rowstride + coloff + ((g & gmask) << 6) + l;
    float x = buf[idx];
    float s = x / (1.f + expf(-x));
    float ss = s * s;
#pragma unroll
    for (int m = 1; m < 64; m <<= 1) ss += __shfl_xor(ss, m);
    float nrm = sqrtf(ss) + 1e-6f;
    buf[idx] = s / nrm;
}

// ------------------------------------------------------------------
// Phase 1: per (bh, chunk) transfer operators (A_c, B_c). CL=64.
// 512 threads: lower half (waves 0-3) carries the A-state, upper half
// (waves 4-7) the B-state. Thread: row i=tt>>2, cols g*16..g*16+15.
// 4-lane reduce via DPP quad-perm (VALU pipe, no DS latency).
// ------------------------------------------------------------------
__global__ __launch_bounds__(512) void k_chunk_transfer(
    const float* __restrict__ proj, const float* __restrict__ maskf,
    float* __restrict__ Ac, float* __restrict__ Bc)
{
    int c = blockIdx.x;
    int bh = blockIdx.y;
    int b = bh >> 3, h = bh & 7;
    int t = threadIdx.x;
    int half = t >> 8;         // 0 = A-state, 1 = B-state
    int tt = t & 255;
    int i = tt >> 2, g = tt & 3;
    __shared__ float sK[CL][128];   // 32 KB
    __shared__ float sV[CL][128];   // 32 KB
    __shared__ float4 sScal[CL];

    size_t tokbase = (size_t)(b * S_ + c * CL);
#pragma unroll
    for (int it = 0; it < (CL * 32) / 512; ++it) {
        int f = it * 512 + t;
        int tok = f >> 5, wi = f & 31;
        *(float4*)&sK[tok][wi * 4] = *(const float4*)&proj[(tokbase + tok) * NPROJ + KOFF + h * 128 + wi * 4];
        *(float4*)&sV[tok][wi * 4] = *(const float4*)&proj[(tokbase + tok) * NPROJ + VOFF + h * 128 + wi * 4];
    }
    if (t < CL) {
        float r0 = proj[(tokbase + t) * NPROJ + BOFF + h * 2 + 0];
        float r1 = proj[(tokbase + t) * NPROJ + BOFF + h * 2 + 1];
        float ms = 1.f - maskf[tokbase + t];
        sScal[t] = make_float4(1.f / (1.f + expf(-r0)), 1.f / (1.f + expf(-r1)), ms, 0.f);
    }
    __syncthreads();

    float St[16];
#pragma unroll
    for (int jl = 0; jl < 16; ++jl)
        St[jl] = (half == 0 && g * 16 + jl == i) ? 1.f : 0.f;

    for (int sl = 0; sl < CL; ++sl) {
        float4 sc = sScal[sl];
        float m1 = sc.z;
#pragma unroll
        for (int jl = 0; jl < 16; ++jl) St[jl] *= m1;
#pragma unroll
        for (int r = 0; r < 2; ++r) {
            float kk[16];
            *(float4*)&kk[0]  = *(const float4*)&sK[sl][r * 64 + g * 16];
            *(float4*)&kk[4]  = *(const float4*)&sK[sl][r * 64 + g * 16 + 4];
            *(float4*)&kk[8]  = *(const float4*)&sK[sl][r * 64 + g * 16 + 8];
            *(float4*)&kk[12] = *(const float4*)&sK[sl][r * 64 + g * 16 + 12];
            float vi = sV[sl][r * 64 + i];
            float br = (r == 0) ? sc.x : sc.y;
            float a0 = 0.f, a1 = 0.f, a2 = 0.f, a3 = 0.f;
#pragma unroll
            for (int q = 0; q < 4; ++q) {
                a0 = fmaf(St[q],      kk[q],      a0);
                a1 = fmaf(St[4 + q],  kk[4 + q],  a1);
                a2 = fmaf(St[8 + q],  kk[8 + q],  a2);
                a3 = fmaf(St[12 + q], kk[12 + q], a3);
            }
            float u = qsum4((a0 + a1) + (a2 + a3));
            float coef = (half == 0) ? (-br * u) : (br * (vi - u));
#pragma unroll
            for (int jl = 0; jl < 16; ++jl)
                St[jl] = fmaf(coef, kk[jl], St[jl]);
        }
    }
    float* dst = (half == 0 ? Ac : Bc) + ((size_t)bh * NC + c) * 4096 + (size_t)i * 64 + g * 16;
#pragma unroll
    for (int q4 = 0; q4 < 4; ++q4)
        *(float4*)&dst[q4 * 4] = *(float4*)&St[q4 * 4];
}

// ------------------------------------------------------------------
// Phase 2: sequential chunk combine, 64 blocks = 16 bh x 4 row-groups
// of 16 rows, NC=16 steps. Async LDS double-buffer for A; Bc
// register-prefetched one step ahead; padded state rows; separate S0.
// ------------------------------------------------------------------
__global__ __launch_bounds__(256) void k_combine(
    const float* __restrict__ Ac, const float* __restrict__ Bc,
    const float* __restrict__ carry, float* __restrict__ S0,
    float* __restrict__ carry_out)
{
    constexpr int SP = 68;
    int blk = blockIdx.x;
    int bh = blk >> 2, rg = blk & 3;
    int t = threadIdx.x;
    int i = t >> 4;              // local row 0..15
    int j0 = (t & 15) * 4;       // col
    int gi = rg * 16 + i;        // global row
    __shared__ float sA[2][64 * 64];   // 32 KB
    __shared__ float sS[16 * SP];

    size_t cb0 = (size_t)bh * NC * 4096;
#pragma unroll
    for (int s = 0; s < 4; ++s)
        gload_lds16(Ac + cb0 + (size_t)(s * 256 + t) * 4, &sA[0][(size_t)(s * 256 + (t & 192)) * 4]);
    float4 rB = *(const float4*)&Bc[cb0 + (size_t)gi * 64 + j0];
    float4 racc = *(const float4*)&carry[(size_t)bh * 4096 + (size_t)gi * 64 + j0];
    *(float4*)&sS[i * SP + j0] = racc;
    asm volatile("s_waitcnt vmcnt(0)" ::: "memory");
    __syncthreads();

    for (int c = 0; c < NC; ++c) {
        int cur = c & 1;
        size_t cb = cb0 + (size_t)c * 4096;
        float4 rBn;
        if (c + 1 < NC) {
#pragma unroll
            for (int s = 0; s < 4; ++s)
                gload_lds16(Ac + cb + 4096 + (size_t)(s * 256 + t) * 4,
                            &sA[cur ^ 1][(size_t)(s * 256 + (t & 192)) * 4]);
            rBn = *(const float4*)&Bc[cb + 4096 + (size_t)gi * 64 + j0];
        }
        *(float4*)&S0[cb + (size_t)gi * 64 + j0] = racc;   // state before chunk c
        float4 acc = rB;
        float4 ac2 = make_float4(0.f, 0.f, 0.f, 0.f);
#pragma unroll
        for (int p4 = 0; p4 < 16; p4 += 2) {
            float4 s0v = *(const float4*)&sS[i * SP + p4 * 4];
            float4 s1v = *(const float4*)&sS[i * SP + p4 * 4 + 4];
            float4 a0 = *(const float4*)&sA[cur][(p4 * 4 + 0) * 64 + j0];
            float4 a1 = *(const float4*)&sA[cur][(p4 * 4 + 1) * 64 + j0];
            float4 a2 = *(const float4*)&sA[cur][(p4 * 4 + 2) * 64 + j0];
            float4 a3 = *(const float4*)&sA[cur][(p4 * 4 + 3) * 64 + j0];
            float4 a4 = *(const float4*)&sA[cur][(p4 * 4 + 4) * 64 + j0];
            float4 a5 = *(const float4*)&sA[cur][(p4 * 4 + 5) * 64 + j0];
            float4 a6 = *(const float4*)&sA[cur][(p4 * 4 + 6) * 64 + j0];
            float4 a7 = *(const float4*)&sA[cur][(p4 * 4 + 7) * 64 + j0];
            acc.x = fmaf(s0v.x, a0.x, acc.x); acc.y = fmaf(s0v.x, a0.y, acc.y);
            acc.z = fmaf(s0v.x, a0.z, acc.z); acc.w = fmaf(s0v.x, a0.w, acc.w);
            ac2.x = fmaf(s0v.y, a1.x, ac2.x); ac2.y = fmaf(s0v.y, a1.y, ac2.y);
            ac2.z = fmaf(s0v.y, a1.z, ac2.z); ac2.w = fmaf(s0v.y, a1.w, ac2.w);
            acc.x = fmaf(s0v.z, a2.x, acc.x); acc.y = fmaf(s0v.z, a2.y, acc.y);
            acc.z = fmaf(s0v.z, a2.z, acc.z); acc.w = fmaf(s0v.z, a2.w, acc.w);
            ac2.x = fmaf(s0v.w, a3.x, ac2.x); ac2.y = fmaf(s0v.w, a3.y, ac2.y);
            ac2.z = fmaf(s0v.w, a3.z, ac2.z); ac2.w = fmaf(s0v.w, a3.w, ac2.w);
            acc.x = fmaf(s1v.x, a4.x, acc.x); acc.y = fmaf(s1v.x, a4.y, acc.y);
            acc.z = fmaf(s1v.x, a4.z, acc.z); acc.w = fmaf(s1v.x, a4.w, acc.w);
            ac2.x = fmaf(s1v.y, a5.x, ac2.x); ac2.y = fmaf(s1v.y, a5.y, ac2.y);
            ac2.z = fmaf(s1v.y, a5.z, ac2.z); ac2.w = fmaf(s1v.y, a5.w, ac2.w);
            acc.x = fmaf(s1v.z, a6.x, acc.x); acc.y = fmaf(s1v.z, a6.y, acc.y);
            acc.z = fmaf(s1v.z, a6.z, acc.z); acc.w = fmaf(s1v.z, a6.w, acc.w);
            ac2.x = fmaf(s1v.w, a7.x, ac2.x); ac2.y = fmaf(s1v.w, a7.y, ac2.y);
            ac2.z = fmaf(s1v.w, a7.z, ac2.z); ac2.w = fmaf(s1v.w, a7.w, ac2.w);
        }
        acc.x += ac2.x; acc.y += ac2.y; acc.z += ac2.z; acc.w += ac2.w;
        __syncthreads();                       // all reads of sS done
        *(float4*)&sS[i * SP + j0] = acc;
        racc = acc;
        rB = rBn;
        asm volatile("s_waitcnt vmcnt(0)" ::: "memory");   // next A staged
        __syncthreads();                       // sS update visible
    }
    *(float4*)&carry_out[(size_t)bh * 4096 + (size_t)gi * 64 + j0] = racc;
}

// ------------------------------------------------------------------
// Phase 3: rerun recurrence from S0, emit x_s = St q_s into the q
// columns of proj. 256 threads, row i = t>>2, cols g*16..+15; DPP
// reduce; K/Q staged in LDS (49 KB -> 3 blocks/CU); V read direct
// from global, prefetched one token ahead.
// ------------------------------------------------------------------
__global__ __launch_bounds__(256) void k_emit_x(
    float* __restrict__ proj, const float* __restrict__ maskf,
    const float* __restrict__ S0)
{
    int c = blockIdx.x;
    int bh = blockIdx.y;
    int b = bh >> 3, h = bh & 7;
    int t = threadIdx.x;
    int i = t >> 2, g = t & 3;
    __shared__ float sK[CL][128];   // 32 KB
    __shared__ float sQ[CL][64];    // 16 KB
    __shared__ float4 sScal[CL];

    size_t tokbase = (size_t)(b * S_ + c * CL);
#pragma unroll
    for (int it = 0; it < (CL * 32) / 256; ++it) {
        int f = it * 256 + t;
        int tok = f >> 5, wi = f & 31;
        *(float4*)&sK[tok][wi * 4] = *(const float4*)&proj[(tokbase + tok) * NPROJ + KOFF + h * 128 + wi * 4];
    }
#pragma unroll
    for (int it = 0; it < (CL * 16) / 256; ++it) {
        int f = it * 256 + t;
        int tok = f >> 4, wi = f & 15;
        *(float4*)&sQ[tok][wi * 4] = *(const float4*)&proj[(tokbase + tok) * NPROJ + QOFF + h * 64 + wi * 4];
    }
    if (t < CL) {
        float r0 = proj[(tokbase + t) * NPROJ + BOFF + h * 2 + 0];
        float r1 = proj[(tokbase + t) * NPROJ + BOFF + h * 2 + 1];
        float ms = 1.f - maskf[tokbase + t];
        sScal[t] = make_float4(1.f / (1.f + expf(-r0)), 1.f / (1.f + expf(-r1)), ms, 0.f);
    }
    __syncthreads();

    float St[16];
    size_t sbase = ((size_t)bh * NC + c) * 4096 + (size_t)i * 64 + g * 16;
#pragma unroll
    for (int q4 = 0; q4 < 4; ++q4)
        *(float4*)&St[q4 * 4] = *(const float4*)&S0[sbase + q4 * 4];

    const float* vbase = &proj[tokbase * NPROJ + VOFF + h * 128];
    float v0 = vbase[i], v1 = vbase[64 + i];

    for (int sl = 0; sl < CL; ++sl) {
        float vc0 = v0, vc1 = v1;
        if (sl + 1 < CL) {
            const float* nb = vbase + (size_t)(sl + 1) * NPROJ;
            v0 = nb[i]; v1 = nb[64 + i];
        }
        float4 sc = sScal[sl];
        float m1 = sc.z;
#pragma unroll
        for (int jl = 0; jl < 16; ++jl) St[jl] *= m1;
#pragma unroll
        for (int r = 0; r < 2; ++r) {
            float kk[16];
            *(float4*)&kk[0]  = *(const float4*)&sK[sl][r * 64 + g * 16];
            *(float4*)&kk[4]  = *(const float4*)&sK[sl][r * 64 + g * 16 + 4];
            *(float4*)&kk[8]  = *(const float4*)&sK[sl][r * 64 + g * 16 + 8];
            *(float4*)&kk[12] = *(const float4*)&sK[sl][r * 64 + g * 16 + 12];
            float vi = (r == 0) ? vc0 : vc1;
            float br = (r == 0) ? sc.x : sc.y;
            float a0 = 0.f, a1 = 0.f, a2 = 0.f, a3 = 0.f;
#pragma unroll
            for (int q = 0; q < 4; ++q) {
                a0 = fmaf(St[q],      kk[q],      a0);
                a1 = fmaf(St[4 + q],  kk[4 + q],  a1);
                a2 = fmaf(St[8 + q],  kk[8 + q],  a2);
                a3 = fmaf(St[12 + q], kk[12 + q], a3);
            }
            float u = qsum4((a0 + a1) + (a2 + a3));
            float coef = br * (vi - u);
#pragma unroll
            for (int jl = 0; jl < 16; ++jl)
                St[jl] = fmaf(coef, kk[jl], St[jl]);
        }
        float qq[16];
        *(float4*)&qq[0]  = *(const float4*)&sQ[sl][g * 16];
        *(float4*)&qq[4]  = *(const float4*)&sQ[sl][g * 16 + 4];
        *(float4*)&qq[8]  = *(const float4*)&sQ[sl][g * 16 + 8];
        *(float4*)&qq[12] = *(const float4*)&sQ[sl][g * 16 + 12];
        float x0 = 0.f, x1 = 0.f, x2 = 0.f, x3 = 0.f;
#pragma unroll
        for (int q = 0; q < 4; ++q) {
            x0 = fmaf(St[q],      qq[q],      x0);
            x1 = fmaf(St[4 + q],  qq[4 + q],  x1);
            x2 = fmaf(St[8 + q],  qq[8 + q],  x2);
            x3 = fmaf(St[12 + q], qq[12 + q], x3);
        }
        float xv = qsum4((x0 + x1) + (x2 + x3));
        if (g == 0) proj[(tokbase + sl) * NPROJ + QOFF + h * 64 + i] = xv;
    }
}

// ------------------------------------------------------------------
// RMS norm over x = proj cols 0..511, * rms_scale, emit compact bf16.
// ------------------------------------------------------------------
__global__ void k_rms_bf16(const float* __restrict__ proj, const float* __restrict__ scale,
                           unsigned short* __restrict__ xo) {
    int w = threadIdx.x >> 6;
    int l = threadIdx.x & 63;
    size_t row = (size_t)blockIdx.x * 4 + w;
    float4 v0 = *(const float4*)&proj[row * NPROJ + l * 8];
    float4 v1 = *(const float4*)&proj[row * NPROJ + l * 8 + 4];
    float ss = v0.x * v0.x + v0.y * v0.y + v0.z * v0.z + v0.w * v0.w
             + v1.x * v1.x + v1.y * v1.y + v1.z * v1.z + v1.w * v1.w;
#pragma unroll
    for (int m = 1; m < 64; m <<= 1) ss += __shfl_xor(ss, m);
    float sc = rsqrtf(ss * (1.f / 512.f) + 1e-6f);
    float4 s0 = *(const float4*)&scale[l * 8];
    float4 s1 = *(const float4*)&scale[l * 8 + 4];
    ushort8 o;
    o[0] = f2bf(v0.x * sc * s0.x); o[1] = f2bf(v0.y * sc * s0.y);
    o[2] = f2bf(v0.z * sc * s0.z); o[3] = f2bf(v0.w * sc * s0.w);
    o[4] = f2bf(v1.x * sc * s1.x); o[5] = f2bf(v1.y * sc * s1.y);
    o[6] = f2bf(v1.z * sc * s1.z); o[7] = f2bf(v1.w * sc * s1.w);
    *(ushort8*)&xo[row * 512 + l * 8] = o;
}

// ------------------------------------------------------------------
extern "C" void kernel_launch(void* const* d_in, const int* in_sizes, int n_in,
                              void* d_out, int out_size, void* d_ws, size_t ws_size,
                              hipStream_t stream) {
    const float* inputs    = (const float*)d_in[0];
    const void*  mask      = d_in[1];
    const float* carry     = (const float*)d_in[2];
    const float* Wq        = (const float*)d_in[3];
    const float* Wk        = (const float*)d_in[4];
    const float* Wv        = (const float*)d_in[5];
    const float* Wb        = (const float*)d_in[6];
    const float* rms_scale = (const float*)d_in[7];
    const float* Wo        = (const float*)d_in[8];
    const float* bo        = (const float*)d_in[9];

    float* out_carry = (float*)d_out;
    float* out_y     = (float*)d_out + (size_t)B_ * H_ * D_ * D_;

    const int M = B_ * S_;  // 2048
    float* ws = (float*)d_ws;
    size_t o = 0;
    float* proj = ws + o; o += (size_t)M * NPROJ;            // 5.37M f
    float* mf   = ws + o; o += (size_t)M;
    float* Ac   = ws + o; o += (size_t)BH * NC * 4096;       // 1M f
    float* Bc   = ws + o; o += (size_t)BH * NC * 4096;       // 1M f
    float* S0   = ws + o; o += (size_t)BH * NC * 4096;       // 1M f
    unsigned short* wt = (unsigned short*)(ws + o); o += (size_t)NPROJ * 512;
    // overlays (lifetimes disjoint):
    unsigned short* inb = (unsigned short*)Bc;   // bf16 inputs (1M f), dead before phase 1 writes Bc
    unsigned short* xbf = (unsigned short*)Ac;   // rms output; Ac dead after combine

    k_mask_prep<<<1, 256, 0, stream>>>(mask, mf, M);
    k_f32_to_bf16<<<(M * 1024) / 1024, 256, 0, stream>>>(inputs, inb, M * 1024);

    // pack W^T = [Wq^T | Wk^T | Wv^T | Wb^T(pad to 64)] as [NPROJ,1024] bf16
    k_transpose_to_bf16<<<dim3(512 / 32, 1024 / 32), 256, 0, stream>>>(Wq, wt + (size_t)QOFF * 1024, 1024, 512);
    k_transpose_to_bf16<<<dim3(1024 / 32, 1024 / 32), 256, 0, stream>>>(Wk, wt + (size_t)KOFF * 1024, 1024, 1024);
    k_transpose_to_bf16<<<dim3(1024 / 32, 1024 / 32), 256, 0, stream>>>(Wv, wt + (size_t)VOFF * 1024, 1024, 1024);
    k_wb_pad<<<64, 256, 0, stream>>>(Wb, wt + (size_t)BOFF * 1024);

    // proj = inputs @ [Wq|Wk|Wv|Wb]
    k_gemm_bf16<<<dim3(NPROJ / 64, M / 128), 256, 0, stream>>>(inb, wt, nullptr, proj, M, NPROJ, 1024);

    // silu+L2norm on q (8 groups/row) and k (16 groups/row)
    k_silu_norm<<<(M * 8) / 4, 256, 0, stream>>>(proj, M * 8, 3, 7, NPROJ, QOFF);
    k_silu_norm<<<(M * 16) / 4, 256, 0, stream>>>(proj, M * 16, 4, 15, NPROJ, KOFF);

    k_chunk_transfer<<<dim3(NC, BH), 512, 0, stream>>>(proj, mf, Ac, Bc);
    k_combine<<<BH * 4, 256, 0, stream>>>(Ac, Bc, carry, S0, out_carry);
    k_emit_x<<<dim3(NC, BH), 256, 0, stream>>>(proj, mf, S0);

    k_rms_bf16<<<M / 4, 256, 0, stream>>>(proj, rms_scale, xbf);

    // y = x @ Wo + bo  (K=512, N=1024); reuse wt for Wo^T
    k_transpose_to_bf16<<<dim3(1024 / 32, 512 / 32), 256, 0, stream>>>(Wo, wt, 512, 1024);
    k_gemm_bf16<<<dim3(1024 / 64, M / 128), 256, 0, stream>>>(xbf, wt, bo, out_y, M, 1024, 512);
}

// Round 10
// 147.535 us; speedup vs baseline: 1.8211x; 1.1223x over previous
//
#include <hip/hip_runtime.h>
#include <hip/hip_bf16.h>

#define B_ 2
#define S_ 1024
#define F_ 1024
#define H_ 8
#define D_ 64
#define R_ 2
#define BH (B_*H_)
#define NC 16
#define CL (S_/NC)   // 64

// combined projection layout: [M, NPROJ] fp32
#define QOFF 0
#define KOFF 512
#define VOFF 1536
#define BOFF 2560
#define NPROJ 2624   // 41 * 64

typedef __bf16 bf16x8 __attribute__((ext_vector_type(8)));
typedef unsigned short ushort8 __attribute__((ext_vector_type(8)));
typedef float f32x4 __attribute__((ext_vector_type(4)));

__device__ __forceinline__ unsigned short f2bf(float f) {
    unsigned u = __builtin_bit_cast(unsigned, f);
    unsigned r = u + 0x7FFFu + ((u >> 16) & 1u);
    return (unsigned short)(r >> 16);
}

__device__ __forceinline__ void gload_lds16(const void* g, void* l) {
    __builtin_amdgcn_global_load_lds(
        (const __attribute__((address_space(1))) void*)g,
        (__attribute__((address_space(3))) void*)l, 16, 0, 0);
}

// DPP quad-perm lane swap (VALU pipe, ~6cy vs ~120cy DS-pipe shfl).
template<int CTRL>
__device__ __forceinline__ float dppf(float x) {
    return __builtin_bit_cast(float, __builtin_amdgcn_update_dpp(
        0, __builtin_bit_cast(int, x), CTRL, 0xF, 0xF, true));
}
__device__ __forceinline__ float qsum4(float x) {
    x += dppf<0xB1>(x);
    x += dppf<0x4E>(x);
    return x;
}

// ------------------------------------------------------------------
// Mask format sniffer + normalize to float 0/1.
// ------------------------------------------------------------------
__global__ void k_mask_prep(const void* __restrict__ mraw, float* __restrict__ maskf, int n) {
    __shared__ int fmt; // 0=int32, 1=byte, 2=float32
    int t = threadIdx.x;
    if (t == 0) fmt = 0;
    __syncthreads();
    const unsigned int* u32 = (const unsigned int*)mraw;
    for (int g = t; g < n / 4; g += blockDim.x) {
        unsigned int v = u32[g];
        if (v == 0x3F800000u) atomicMax(&fmt, 2);
        else if (v != 0u && v != 1u) atomicMax(&fmt, 1);
    }
    __syncthreads();
    int f = fmt;
    const unsigned char* u8 = (const unsigned char*)mraw;
    const float* f32 = (const float*)mraw;
    for (int i = t; i < n; i += blockDim.x) {
        float mv;
        if (f == 1)      mv = u8[i] ? 1.f : 0.f;
        else if (f == 2) mv = (f32[i] != 0.f) ? 1.f : 0.f;
        else             mv = (u32[i] != 0u) ? 1.f : 0.f;
        maskf[i] = mv;
    }
}

// ------------------------------------------------------------------
// fp32 -> bf16 elementwise (n % 4 == 0)
// ------------------------------------------------------------------
__global__ void k_f32_to_bf16(const float* __restrict__ s, unsigned short* __restrict__ d, int n) {
    int i = (blockIdx.x * blockDim.x + threadIdx.x) * 4;
    if (i < n) {
        float4 v = *(const float4*)&s[i];
        d[i + 0] = f2bf(v.x); d[i + 1] = f2bf(v.y);
        d[i + 2] = f2bf(v.z); d[i + 3] = f2bf(v.w);
    }
}

// ------------------------------------------------------------------
// Transpose [K,N] f32 -> [N,K] bf16. 32x32 tiles, 256 threads.
// ------------------------------------------------------------------
__global__ __launch_bounds__(256) void k_transpose_to_bf16(
    const float* __restrict__ src, unsigned short* __restrict__ dst, int K, int N)
{
    __shared__ float tile[32][33];
    int bx = blockIdx.x, by = blockIdx.y;
    int tx = threadIdx.x & 31, ty = threadIdx.x >> 5;
#pragma unroll
    for (int i = 0; i < 32; i += 8)
        tile[ty + i][tx] = src[(size_t)(by * 32 + ty + i) * N + bx * 32 + tx];
    __syncthreads();
#pragma unroll
    for (int i = 0; i < 32; i += 8)
        dst[(size_t)(bx * 32 + ty + i) * K + by * 32 + tx] = f2bf(tile[tx][ty + i]);
}

// ------------------------------------------------------------------
// Wb [1024,16] f32 -> rows BOFF..BOFF+63 of wt as [64,1024] bf16.
// ------------------------------------------------------------------
__global__ void k_wb_pad(const float* __restrict__ Wb, unsigned short* __restrict__ dst) {
    int row = blockIdx.x;
    int c0 = threadIdx.x * 4;
#pragma unroll
    for (int c = c0; c < c0 + 4; ++c)
        dst[(size_t)row * 1024 + c] = (row < 16) ? f2bf(Wb[(size_t)c * 16 + row]) : (unsigned short)0;
}

// ------------------------------------------------------------------
// bf16 MFMA GEMM: C[M,N] = A[M,K] @ B[K,N] (+bias). Tile 128x64, BK=64.
// ------------------------------------------------------------------
__global__ __launch_bounds__(256) void k_gemm_bf16(
    const unsigned short* __restrict__ A, const unsigned short* __restrict__ Bt,
    const float* __restrict__ bias, float* __restrict__ C,
    int M, int N, int K)
{
    constexpr int BM = 128, BN = 64, BK = 64;
    __shared__ unsigned short sA[BM * BK];
    __shared__ unsigned short sB[BN * BK];
    int t = threadIdx.x;
    int w = t >> 6, l = t & 63;
    int rowb = blockIdx.y * BM, colb = blockIdx.x * BN;
    int wr = w >> 1, wc = w & 1;
    int fr = l & 15, kgrp = l >> 4;

    f32x4 acc[4][2];
#pragma unroll
    for (int m = 0; m < 4; ++m)
#pragma unroll
        for (int n = 0; n < 2; ++n) acc[m][n] = (f32x4){0.f, 0.f, 0.f, 0.f};

    int lrow_off = l >> 3;
    int kg_phys = l & 7;

    for (int k0 = 0; k0 < K; k0 += BK) {
        __syncthreads();
#pragma unroll
        for (int is = 0; is < 4; ++is) {
            int r0 = (w * 4 + is) * 8;
            int row = r0 + lrow_off;
            int kg_log = kg_phys ^ (row & 7);
            gload_lds16(A + (size_t)(rowb + row) * K + k0 + kg_log * 8, &sA[r0 * BK]);
        }
#pragma unroll
        for (int is = 0; is < 2; ++is) {
            int r0 = (w * 2 + is) * 8;
            int row = r0 + lrow_off;
            int kg_log = kg_phys ^ (row & 7);
            gload_lds16(Bt + (size_t)(colb + row) * K + k0 + kg_log * 8, &sB[r0 * BK]);
        }
        asm volatile("s_waitcnt vmcnt(0)" ::: "memory");
        __syncthreads();

#pragma unroll
        for (int kk = 0; kk < BK; kk += 32) {
            int kg = (kk >> 3) + kgrp;
            bf16x8 af[4], bfv[2];
#pragma unroll
            for (int m = 0; m < 4; ++m) {
                int row = wr * 64 + m * 16 + fr;
                ushort8 raw = *(const ushort8*)&sA[row * BK + (kg ^ (row & 7)) * 8];
                af[m] = __builtin_bit_cast(bf16x8, raw);
            }
#pragma unroll
            for (int n = 0; n < 2; ++n) {
                int row = wc * 32 + n * 16 + fr;
                ushort8 raw = *(const ushort8*)&sB[row * BK + (kg ^ (row & 7)) * 8];
                bfv[n] = __builtin_bit_cast(bf16x8, raw);
            }
#pragma unroll
            for (int m = 0; m < 4; ++m)
#pragma unroll
                for (int n = 0; n < 2; ++n)
                    acc[m][n] = __builtin_amdgcn_mfma_f32_16x16x32_bf16(af[m], bfv[n], acc[m][n], 0, 0, 0);
        }
    }

#pragma unroll
    for (int m = 0; m < 4; ++m)
#pragma unroll
        for (int n = 0; n < 2; ++n) {
            int grow0 = rowb + wr * 64 + m * 16 + kgrp * 4;
            int gcol  = colb + wc * 32 + n * 16 + fr;
            float bv = bias ? bias[gcol] : 0.f;
#pragma unroll
            for (int r = 0; r < 4; ++r)
                C[(size_t)(grow0 + r) * N + gcol] = acc[m][n][r] + bv;
        }
}

// ------------------------------------------------------------------
// silu then L2-normalize per group of 64 with strided row layout.
// ------------------------------------------------------------------
__global__ void k_silu_norm(float* __restrict__ buf, int ngroups,
                            int gshift, int gmask, int rowstride, int coloff) {
    int w = threadIdx.x >> 6;
    int l = threadIdx.x & 63;
    int g = blockIdx.x * 4 + w;
    if (g >= ngroups) return;
    size_t idx = (size_t)(g >> gshift) * rowstride + coloff + ((g & gmask) << 6) + l;
    float x = buf[idx];
    float s = x / (1.f + expf(-x));
    float ss = s * s;
#pragma unroll
    for (int m = 1; m < 64; m <<= 1) ss += __shfl_xor(ss, m);
    float nrm = sqrtf(ss) + 1e-6f;
    buf[idx] = s / nrm;
}

// ------------------------------------------------------------------
// Phase 1: per (bh, chunk): transfer ops (A_c, B_c) AND per-token
// projected vectors a_s = A^pre_s q_s, b_s = B^pre_s q_s (-> ab).
// 512 threads: lower half = A-state, upper half = B-state.
// K,Q staged in LDS; V (B-half only) direct global, prefetched.
// ------------------------------------------------------------------
__global__ __launch_bounds__(512) void k_chunk_transfer(
    const float* __restrict__ proj, const float* __restrict__ maskf,
    float* __restrict__ Ac, float* __restrict__ Bc, float* __restrict__ ab)
{
    int c = blockIdx.x;
    int bh = blockIdx.y;
    int b = bh >> 3, h = bh & 7;
    int t = threadIdx.x;
    int half = t >> 8;         // 0 = A-state, 1 = B-state
    int tt = t & 255;
    int i = tt >> 2, g = tt & 3;
    __shared__ float sK[CL][128];   // 32 KB
    __shared__ float sQ[CL][64];    // 16 KB
    __shared__ float4 sScal[CL];

    size_t tokbase = (size_t)(b * S_ + c * CL);
#pragma unroll
    for (int it = 0; it < (CL * 32) / 512; ++it) {
        int f = it * 512 + t;
        int tok = f >> 5, wi = f & 31;
        *(float4*)&sK[tok][wi * 4] = *(const float4*)&proj[(tokbase + tok) * NPROJ + KOFF + h * 128 + wi * 4];
    }
#pragma unroll
    for (int it = 0; it < (CL * 16) / 512; ++it) {
        int f = it * 512 + t;
        int tok = f >> 4, wi = f & 15;
        *(float4*)&sQ[tok][wi * 4] = *(const float4*)&proj[(tokbase + tok) * NPROJ + QOFF + h * 64 + wi * 4];
    }
    if (t < CL) {
        float r0 = proj[(tokbase + t) * NPROJ + BOFF + h * 2 + 0];
        float r1 = proj[(tokbase + t) * NPROJ + BOFF + h * 2 + 1];
        float ms = 1.f - maskf[tokbase + t];
        sScal[t] = make_float4(1.f / (1.f + expf(-r0)), 1.f / (1.f + expf(-r1)), ms, 0.f);
    }
    __syncthreads();

    float St[16];
#pragma unroll
    for (int jl = 0; jl < 16; ++jl)
        St[jl] = (half == 0 && g * 16 + jl == i) ? 1.f : 0.f;

    const float* vbase = &proj[tokbase * NPROJ + VOFF + h * 128];
    float v0 = 0.f, v1 = 0.f;
    if (half) { v0 = vbase[i]; v1 = vbase[64 + i]; }

    float* abdst = ab + ((size_t)bh * NC + c) * (size_t)(CL * 128) + half * 64 + i;

    for (int sl = 0; sl < CL; ++sl) {
        float vc0 = v0, vc1 = v1;
        if (half && sl + 1 < CL) {
            const float* nb = vbase + (size_t)(sl + 1) * NPROJ;
            v0 = nb[i]; v1 = nb[64 + i];
        }
        float4 sc = sScal[sl];
        if (sc.z == 0.f) {           // masked token: state reset (block-uniform, ~5%)
#pragma unroll
            for (int jl = 0; jl < 16; ++jl) St[jl] = 0.f;
        }
#pragma unroll
        for (int r = 0; r < 2; ++r) {
            float kk[16];
            *(float4*)&kk[0]  = *(const float4*)&sK[sl][r * 64 + g * 16];
            *(float4*)&kk[4]  = *(const float4*)&sK[sl][r * 64 + g * 16 + 4];
            *(float4*)&kk[8]  = *(const float4*)&sK[sl][r * 64 + g * 16 + 8];
            *(float4*)&kk[12] = *(const float4*)&sK[sl][r * 64 + g * 16 + 12];
            float vi = (r == 0) ? vc0 : vc1;
            float br = (r == 0) ? sc.x : sc.y;
            float a0 = 0.f, a1 = 0.f, a2 = 0.f, a3 = 0.f;
#pragma unroll
            for (int q = 0; q < 4; ++q) {
                a0 = fmaf(St[q],      kk[q],      a0);
                a1 = fmaf(St[4 + q],  kk[4 + q],  a1);
                a2 = fmaf(St[8 + q],  kk[8 + q],  a2);
                a3 = fmaf(St[12 + q], kk[12 + q], a3);
            }
            float u = qsum4((a0 + a1) + (a2 + a3));
            float coef = (half == 0) ? (-br * u) : (br * (vi - u));
#pragma unroll
            for (int jl = 0; jl < 16; ++jl)
                St[jl] = fmaf(coef, kk[jl], St[jl]);
        }
        // per-token projected vector: (state after token sl) . q_sl
        float qq[16];
        *(float4*)&qq[0]  = *(const float4*)&sQ[sl][g * 16];
        *(float4*)&qq[4]  = *(const float4*)&sQ[sl][g * 16 + 4];
        *(float4*)&qq[8]  = *(const float4*)&sQ[sl][g * 16 + 8];
        *(float4*)&qq[12] = *(const float4*)&sQ[sl][g * 16 + 12];
        float x0 = 0.f, x1 = 0.f, x2 = 0.f, x3 = 0.f;
#pragma unroll
        for (int q = 0; q < 4; ++q) {
            x0 = fmaf(St[q],      qq[q],      x0);
            x1 = fmaf(St[4 + q],  qq[4 + q],  x1);
            x2 = fmaf(St[8 + q],  qq[8 + q],  x2);
            x3 = fmaf(St[12 + q], qq[12 + q], x3);
        }
        float xv = qsum4((x0 + x1) + (x2 + x3));
        if (g == 0) abdst[sl * 128] = xv;
    }
    float* dst = (half == 0 ? Ac : Bc) + ((size_t)bh * NC + c) * 4096 + (size_t)i * 64 + g * 16;
#pragma unroll
    for (int q4 = 0; q4 < 4; ++q4)
        *(float4*)&dst[q4 * 4] = *(float4*)&St[q4 * 4];
}

// ------------------------------------------------------------------
// Phase 2: sequential chunk combine, 64 blocks = 16 bh x 4 row-groups
// of 16 rows, NC=16 steps. Async LDS double-buffer for A; Bc
// register-prefetched one step ahead; padded state rows; separate S0.
// ------------------------------------------------------------------
__global__ __launch_bounds__(256) void k_combine(
    const float* __restrict__ Ac, const float* __restrict__ Bc,
    const float* __restrict__ carry, float* __restrict__ S0,
    float* __restrict__ carry_out)
{
    constexpr int SP = 68;
    int blk = blockIdx.x;
    int bh = blk >> 2, rg = blk & 3;
    int t = threadIdx.x;
    int i = t >> 4;
    int j0 = (t & 15) * 4;
    int gi = rg * 16 + i;
    __shared__ float sA[2][64 * 64];
    __shared__ float sS[16 * SP];

    size_t cb0 = (size_t)bh * NC * 4096;
#pragma unroll
    for (int s = 0; s < 4; ++s)
        gload_lds16(Ac + cb0 + (size_t)(s * 256 + t) * 4, &sA[0][(size_t)(s * 256 + (t & 192)) * 4]);
    float4 rB = *(const float4*)&Bc[cb0 + (size_t)gi * 64 + j0];
    float4 racc = *(const float4*)&carry[(size_t)bh * 4096 + (size_t)gi * 64 + j0];
    *(float4*)&sS[i * SP + j0] = racc;
    asm volatile("s_waitcnt vmcnt(0)" ::: "memory");
    __syncthreads();

    for (int c = 0; c < NC; ++c) {
        int cur = c & 1;
        size_t cb = cb0 + (size_t)c * 4096;
        float4 rBn;
        if (c + 1 < NC) {
#pragma unroll
            for (int s = 0; s < 4; ++s)
                gload_lds16(Ac + cb + 4096 + (size_t)(s * 256 + t) * 4,
                            &sA[cur ^ 1][(size_t)(s * 256 + (t & 192)) * 4]);
            rBn = *(const float4*)&Bc[cb + 4096 + (size_t)gi * 64 + j0];
        }
        *(float4*)&S0[cb + (size_t)gi * 64 + j0] = racc;
        float4 acc = rB;
        float4 ac2 = make_float4(0.f, 0.f, 0.f, 0.f);
#pragma unroll
        for (int p4 = 0; p4 < 16; p4 += 2) {
            float4 s0v = *(const float4*)&sS[i * SP + p4 * 4];
            float4 s1v = *(const float4*)&sS[i * SP + p4 * 4 + 4];
            float4 a0 = *(const float4*)&sA[cur][(p4 * 4 + 0) * 64 + j0];
            float4 a1 = *(const float4*)&sA[cur][(p4 * 4 + 1) * 64 + j0];
            float4 a2 = *(const float4*)&sA[cur][(p4 * 4 + 2) * 64 + j0];
            float4 a3 = *(const float4*)&sA[cur][(p4 * 4 + 3) * 64 + j0];
            float4 a4 = *(const float4*)&sA[cur][(p4 * 4 + 4) * 64 + j0];
            float4 a5 = *(const float4*)&sA[cur][(p4 * 4 + 5) * 64 + j0];
            float4 a6 = *(const float4*)&sA[cur][(p4 * 4 + 6) * 64 + j0];
            float4 a7 = *(const float4*)&sA[cur][(p4 * 4 + 7) * 64 + j0];
            acc.x = fmaf(s0v.x, a0.x, acc.x); acc.y = fmaf(s0v.x, a0.y, acc.y);
            acc.z = fmaf(s0v.x, a0.z, acc.z); acc.w = fmaf(s0v.x, a0.w, acc.w);
            ac2.x = fmaf(s0v.y, a1.x, ac2.x); ac2.y = fmaf(s0v.y, a1.y, ac2.y);
            ac2.z = fmaf(s0v.y, a1.z, ac2.z); ac2.w = fmaf(s0v.y, a1.w, ac2.w);
            acc.x = fmaf(s0v.z, a2.x, acc.x); acc.y = fmaf(s0v.z, a2.y, acc.y);
            acc.z = fmaf(s0v.z, a2.z, acc.z); acc.w = fmaf(s0v.z, a2.w, acc.w);
            ac2.x = fmaf(s0v.w, a3.x, ac2.x); ac2.y = fmaf(s0v.w, a3.y, ac2.y);
            ac2.z = fmaf(s0v.w, a3.z, ac2.z); ac2.w = fmaf(s0v.w, a3.w, ac2.w);
            acc.x = fmaf(s1v.x, a4.x, acc.x); acc.y = fmaf(s1v.x, a4.y, acc.y);
            acc.z = fmaf(s1v.x, a4.z, acc.z); acc.w = fmaf(s1v.x, a4.w, acc.w);
            ac2.x = fmaf(s1v.y, a5.x, ac2.x); ac2.y = fmaf(s1v.y, a5.y, ac2.y);
            ac2.z = fmaf(s1v.y, a5.z, ac2.z); ac2.w = fmaf(s1v.y, a5.w, ac2.w);
            acc.x = fmaf(s1v.z, a6.x, acc.x); acc.y = fmaf(s1v.z, a6.y, acc.y);
            acc.z = fmaf(s1v.z, a6.z, acc.z); acc.w = fmaf(s1v.z, a6.w, acc.w);
            ac2.x = fmaf(s1v.w, a7.x, ac2.x); ac2.y = fmaf(s1v.w, a7.y, ac2.y);
            ac2.z = fmaf(s1v.w, a7.z, ac2.z); ac2.w = fmaf(s1v.w, a7.w, ac2.w);
        }
        acc.x += ac2.x; acc.y += ac2.y; acc.z += ac2.z; acc.w += ac2.w;
        __syncthreads();
        *(float4*)&sS[i * SP + j0] = acc;
        racc = acc;
        rB = rBn;
        asm volatile("s_waitcnt vmcnt(0)" ::: "memory");
        __syncthreads();
    }
    *(float4*)&carry_out[(size_t)bh * 4096 + (size_t)gi * 64 + j0] = racc;
}

// ------------------------------------------------------------------
// Phase 3 (new): X_chunk = Aa @ S0^T + Bb  per (bh, chunk).
// ab[(bh,c)][s][half][i]: half 0 = a_s, half 1 = b_s.
// Transposed staging (pad 67); thread computes 4 tokens x 4 dims.
// Writes x into proj q-columns.
// ------------------------------------------------------------------
__global__ __launch_bounds__(256) void k_xgemm(
    const float* __restrict__ ab, const float* __restrict__ S0,
    float* __restrict__ proj)
{
    constexpr int P = 67;
    int c = blockIdx.x, bh = blockIdx.y;
    int b = bh >> 3, h = bh & 7;
    int t = threadIdx.x;
    __shared__ float sAaT[64 * P];   // Aa^T : [p][s]
    __shared__ float sS0T[64 * P];   // S0^T : [p][i]
    size_t abbase = ((size_t)bh * NC + c) * (size_t)(CL * 128);
    size_t s0base = ((size_t)bh * NC + c) * 4096;

#pragma unroll
    for (int it = 0; it < 4; ++it) {
        int f = it * 256 + t;
        int r = f >> 4, p0 = (f & 15) * 4;
        float4 va = *(const float4*)&ab[abbase + (size_t)r * 128 + p0];      // Aa[s=r][p0..]
        sAaT[(p0 + 0) * P + r] = va.x; sAaT[(p0 + 1) * P + r] = va.y;
        sAaT[(p0 + 2) * P + r] = va.z; sAaT[(p0 + 3) * P + r] = va.w;
        float4 vs = *(const float4*)&S0[s0base + (size_t)r * 64 + p0];       // S0[i=r][p0..]
        sS0T[(p0 + 0) * P + r] = vs.x; sS0T[(p0 + 1) * P + r] = vs.y;
        sS0T[(p0 + 2) * P + r] = vs.z; sS0T[(p0 + 3) * P + r] = vs.w;
    }
    __syncthreads();

    int s0r = (t >> 4) * 4;     // 4 tokens
    int i0 = (t & 15) * 4;      // 4 dims
    size_t tokbase = (size_t)(b * S_ + c * CL);
    float4 acc[4];
#pragma unroll
    for (int a = 0; a < 4; ++a)
        acc[a] = *(const float4*)&ab[abbase + (size_t)(s0r + a) * 128 + 64 + i0];  // Bb
#pragma unroll 8
    for (int p = 0; p < 64; ++p) {
        float4 aa = *(const float4*)&sAaT[p * P + s0r];
        float4 ss = *(const float4*)&sS0T[p * P + i0];
        acc[0].x = fmaf(aa.x, ss.x, acc[0].x); acc[0].y = fmaf(aa.x, ss.y, acc[0].y);
        acc[0].z = fmaf(aa.x, ss.z, acc[0].z); acc[0].w = fmaf(aa.x, ss.w, acc[0].w);
        acc[1].x = fmaf(aa.y, ss.x, acc[1].x); acc[1].y = fmaf(aa.y, ss.y, acc[1].y);
        acc[1].z = fmaf(aa.y, ss.z, acc[1].z); acc[1].w = fmaf(aa.y, ss.w, acc[1].w);
        acc[2].x = fmaf(aa.z, ss.x, acc[2].x); acc[2].y = fmaf(aa.z, ss.y, acc[2].y);
        acc[2].z = fmaf(aa.z, ss.z, acc[2].z); acc[2].w = fmaf(aa.z, ss.w, acc[2].w);
        acc[3].x = fmaf(aa.w, ss.x, acc[3].x); acc[3].y = fmaf(aa.w, ss.y, acc[3].y);
        acc[3].z = fmaf(aa.w, ss.z, acc[3].z); acc[3].w = fmaf(aa.w, ss.w, acc[3].w);
    }
#pragma unroll
    for (int a = 0; a < 4; ++a)
        *(float4*)&proj[(tokbase + s0r + a) * NPROJ + QOFF + h * 64 + i0] = acc[a];
}

// ------------------------------------------------------------------
// RMS norm over x = proj cols 0..511, * rms_scale, emit compact bf16.
// ------------------------------------------------------------------
__global__ void k_rms_bf16(const float* __restrict__ proj, const float* __restrict__ scale,
                           unsigned short* __restrict__ xo) {
    int w = threadIdx.x >> 6;
    int l = threadIdx.x & 63;
    size_t row = (size_t)blockIdx.x * 4 + w;
    float4 v0 = *(const float4*)&proj[row * NPROJ + l * 8];
    float4 v1 = *(const float4*)&proj[row * NPROJ + l * 8 + 4];
    float ss = v0.x * v0.x + v0.y * v0.y + v0.z * v0.z + v0.w * v0.w
             + v1.x * v1.x + v1.y * v1.y + v1.z * v1.z + v1.w * v1.w;
#pragma unroll
    for (int m = 1; m < 64; m <<= 1) ss += __shfl_xor(ss, m);
    float sc = rsqrtf(ss * (1.f / 512.f) + 1e-6f);
    float4 s0 = *(const float4*)&scale[l * 8];
    float4 s1 = *(const float4*)&scale[l * 8 + 4];
    ushort8 o;
    o[0] = f2bf(v0.x * sc * s0.x); o[1] = f2bf(v0.y * sc * s0.y);
    o[2] = f2bf(v0.z * sc * s0.z); o[3] = f2bf(v0.w * sc * s0.w);
    o[4] = f2bf(v1.x * sc * s1.x); o[5] = f2bf(v1.y * sc * s1.y);
    o[6] = f2bf(v1.z * sc * s1.z); o[7] = f2bf(v1.w * sc * s1.w);
    *(ushort8*)&xo[row * 512 + l * 8] = o;
}

// ------------------------------------------------------------------
extern "C" void kernel_launch(void* const* d_in, const int* in_sizes, int n_in,
                              void* d_out, int out_size, void* d_ws, size_t ws_size,
                              hipStream_t stream) {
    const float* inputs    = (const float*)d_in[0];
    const void*  mask      = d_in[1];
    const float* carry     = (const float*)d_in[2];
    const float* Wq        = (const float*)d_in[3];
    const float* Wk        = (const float*)d_in[4];
    const float* Wv        = (const float*)d_in[5];
    const float* Wb        = (const float*)d_in[6];
    const float* rms_scale = (const float*)d_in[7];
    const float* Wo        = (const float*)d_in[8];
    const float* bo        = (const float*)d_in[9];

    float* out_carry = (float*)d_out;
    float* out_y     = (float*)d_out + (size_t)B_ * H_ * D_ * D_;

    const int M = B_ * S_;  // 2048
    float* ws = (float*)d_ws;
    size_t o = 0;
    float* proj = ws + o; o += (size_t)M * NPROJ;            // 5.37M f
    float* mf   = ws + o; o += (size_t)M;
    float* Ac   = ws + o; o += (size_t)BH * NC * 4096;       // 1M f
    float* Bc   = ws + o; o += (size_t)BH * NC * 4096;       // 1M f
    float* S0   = ws + o; o += (size_t)BH * NC * 4096;       // 1M f
    float* abuf = ws + o; o += (size_t)BH * NC * CL * 128;   // 2M f
    unsigned short* wt = (unsigned short*)(ws + o); o += (size_t)NPROJ * 512;
    // overlays (lifetimes disjoint):
    unsigned short* inb = (unsigned short*)Bc;   // bf16 inputs, dead before transfer writes Bc
    unsigned short* xbf = (unsigned short*)Ac;   // rms output; Ac dead after combine

    k_mask_prep<<<1, 256, 0, stream>>>(mask, mf, M);
    k_f32_to_bf16<<<(M * 1024) / 1024, 256, 0, stream>>>(inputs, inb, M * 1024);

    // pack W^T = [Wq^T | Wk^T | Wv^T | Wb^T(pad to 64)] as [NPROJ,1024] bf16
    k_transpose_to_bf16<<<dim3(512 / 32, 1024 / 32), 256, 0, stream>>>(Wq, wt + (size_t)QOFF * 1024, 1024, 512);
    k_transpose_to_bf16<<<dim3(1024 / 32, 1024 / 32), 256, 0, stream>>>(Wk, wt + (size_t)KOFF * 1024, 1024, 1024);
    k_transpose_to_bf16<<<dim3(1024 / 32, 1024 / 32), 256, 0, stream>>>(Wv, wt + (size_t)VOFF * 1024, 1024, 1024);
    k_wb_pad<<<64, 256, 0, stream>>>(Wb, wt + (size_t)BOFF * 1024);

    // proj = inputs @ [Wq|Wk|Wv|Wb]
    k_gemm_bf16<<<dim3(NPROJ / 64, M / 128), 256, 0, stream>>>(inb, wt, nullptr, proj, M, NPROJ, 1024);

    // silu+L2norm on q (8 groups/row) and k (16 groups/row)
    k_silu_norm<<<(M * 8) / 4, 256, 0, stream>>>(proj, M * 8, 3, 7, NPROJ, QOFF);
    k_silu_norm<<<(M * 16) / 4, 256, 0, stream>>>(proj, M * 16, 4, 15, NPROJ, KOFF);

    // scan: transfer (+ per-token a,b vectors) -> combine -> X = Aa@S0^T + Bb
    k_chunk_transfer<<<dim3(NC, BH), 512, 0, stream>>>(proj, mf, Ac, Bc, abuf);
    k_combine<<<BH * 4, 256, 0, stream>>>(Ac, Bc, carry, S0, out_carry);
    k_xgemm<<<dim3(NC, BH), 256, 0, stream>>>(abuf, S0, proj);

    k_rms_bf16<<<M / 4, 256, 0, stream>>>(proj, rms_scale, xbf);

    // y = x @ Wo + bo  (K=512, N=1024); reuse wt for Wo^T
    k_transpose_to_bf16<<<dim3(1024 / 32, 512 / 32), 256, 0, stream>>>(Wo, wt, 512, 1024);
    k_gemm_bf16<<<dim3(1024 / 64, M / 128), 256, 0, stream>>>(xbf, wt, bo, out_y, M, 1024, 512);
}

// Round 11
// 138.136 us; speedup vs baseline: 1.9450x; 1.0680x over previous
//
#include <hip/hip_runtime.h>
#include <hip/hip_bf16.h>

#define B_ 2
#define S_ 1024
#define F_ 1024
#define H_ 8
#define D_ 64
#define R_ 2
#define BH (B_*H_)
#define NC 16
#define CL (S_/NC)   // 64

// combined projection layout: [M, NPROJ] fp32
#define QOFF 0
#define KOFF 512
#define VOFF 1536
#define BOFF 2560
#define NPROJ 2624   // 41 * 64

typedef __bf16 bf16x8 __attribute__((ext_vector_type(8)));
typedef unsigned short ushort8 __attribute__((ext_vector_type(8)));
typedef float f32x4 __attribute__((ext_vector_type(4)));

__device__ __forceinline__ unsigned short f2bf(float f) {
    unsigned u = __builtin_bit_cast(unsigned, f);
    unsigned r = u + 0x7FFFu + ((u >> 16) & 1u);
    return (unsigned short)(r >> 16);
}

__device__ __forceinline__ void gload_lds16(const void* g, void* l) {
    __builtin_amdgcn_global_load_lds(
        (const __attribute__((address_space(1))) void*)g,
        (__attribute__((address_space(3))) void*)l, 16, 0, 0);
}

// DPP lane swaps (VALU pipe, ~6cy vs ~120cy DS-pipe shfl).
template<int CTRL>
__device__ __forceinline__ float dppf(float x) {
    return __builtin_bit_cast(float, __builtin_amdgcn_update_dpp(
        0, __builtin_bit_cast(int, x), CTRL, 0xF, 0xF, true));
}
// sum across each aligned 4-lane quad
__device__ __forceinline__ float qsum4(float x) {
    x += dppf<0xB1>(x);   // quad perm [1,0,3,2]
    x += dppf<0x4E>(x);   // quad perm [2,3,0,1]
    return x;
}
// sum across each aligned 8-lane group
__device__ __forceinline__ float qsum8(float x) {
    x += dppf<0xB1>(x);
    x += dppf<0x4E>(x);
    x += dppf<0x141>(x);  // ROW_HALF_MIRROR: lane i <-> 7-i within 8
    return x;
}

// ------------------------------------------------------------------
// Mask format sniffer + normalize to float 0/1.
// ------------------------------------------------------------------
__global__ void k_mask_prep(const void* __restrict__ mraw, float* __restrict__ maskf, int n) {
    __shared__ int fmt; // 0=int32, 1=byte, 2=float32
    int t = threadIdx.x;
    if (t == 0) fmt = 0;
    __syncthreads();
    const unsigned int* u32 = (const unsigned int*)mraw;
    for (int g = t; g < n / 4; g += blockDim.x) {
        unsigned int v = u32[g];
        if (v == 0x3F800000u) atomicMax(&fmt, 2);
        else if (v != 0u && v != 1u) atomicMax(&fmt, 1);
    }
    __syncthreads();
    int f = fmt;
    const unsigned char* u8 = (const unsigned char*)mraw;
    const float* f32 = (const float*)mraw;
    for (int i = t; i < n; i += blockDim.x) {
        float mv;
        if (f == 1)      mv = u8[i] ? 1.f : 0.f;
        else if (f == 2) mv = (f32[i] != 0.f) ? 1.f : 0.f;
        else             mv = (u32[i] != 0u) ? 1.f : 0.f;
        maskf[i] = mv;
    }
}

// ------------------------------------------------------------------
// fp32 -> bf16 elementwise (n % 4 == 0)
// ------------------------------------------------------------------
__global__ void k_f32_to_bf16(const float* __restrict__ s, unsigned short* __restrict__ d, int n) {
    int i = (blockIdx.x * blockDim.x + threadIdx.x) * 4;
    if (i < n) {
        float4 v = *(const float4*)&s[i];
        d[i + 0] = f2bf(v.x); d[i + 1] = f2bf(v.y);
        d[i + 2] = f2bf(v.z); d[i + 3] = f2bf(v.w);
    }
}

// ------------------------------------------------------------------
// Transpose [K,N] f32 -> [N,K] bf16. 32x32 tiles, 256 threads.
// ------------------------------------------------------------------
__global__ __launch_bounds__(256) void k_transpose_to_bf16(
    const float* __restrict__ src, unsigned short* __restrict__ dst, int K, int N)
{
    __shared__ float tile[32][33];
    int bx = blockIdx.x, by = blockIdx.y;
    int tx = threadIdx.x & 31, ty = threadIdx.x >> 5;
#pragma unroll
    for (int i = 0; i < 32; i += 8)
        tile[ty + i][tx] = src[(size_t)(by * 32 + ty + i) * N + bx * 32 + tx];
    __syncthreads();
#pragma unroll
    for (int i = 0; i < 32; i += 8)
        dst[(size_t)(bx * 32 + ty + i) * K + by * 32 + tx] = f2bf(tile[tx][ty + i]);
}

// ------------------------------------------------------------------
// Wb [1024,16] f32 -> rows BOFF..BOFF+63 of wt as [64,1024] bf16.
// ------------------------------------------------------------------
__global__ void k_wb_pad(const float* __restrict__ Wb, unsigned short* __restrict__ dst) {
    int row = blockIdx.x;
    int c0 = threadIdx.x * 4;
#pragma unroll
    for (int c = c0; c < c0 + 4; ++c)
        dst[(size_t)row * 1024 + c] = (row < 16) ? f2bf(Wb[(size_t)c * 16 + row]) : (unsigned short)0;
}

// ------------------------------------------------------------------
// bf16 MFMA GEMM: C[M,N] = A[M,K] @ B[K,N] (+bias). Tile 128x64, BK=64.
// ------------------------------------------------------------------
__global__ __launch_bounds__(256) void k_gemm_bf16(
    const unsigned short* __restrict__ A, const unsigned short* __restrict__ Bt,
    const float* __restrict__ bias, float* __restrict__ C,
    int M, int N, int K)
{
    constexpr int BM = 128, BN = 64, BK = 64;
    __shared__ unsigned short sA[BM * BK];
    __shared__ unsigned short sB[BN * BK];
    int t = threadIdx.x;
    int w = t >> 6, l = t & 63;
    int rowb = blockIdx.y * BM, colb = blockIdx.x * BN;
    int wr = w >> 1, wc = w & 1;
    int fr = l & 15, kgrp = l >> 4;

    f32x4 acc[4][2];
#pragma unroll
    for (int m = 0; m < 4; ++m)
#pragma unroll
        for (int n = 0; n < 2; ++n) acc[m][n] = (f32x4){0.f, 0.f, 0.f, 0.f};

    int lrow_off = l >> 3;
    int kg_phys = l & 7;

    for (int k0 = 0; k0 < K; k0 += BK) {
        __syncthreads();
#pragma unroll
        for (int is = 0; is < 4; ++is) {
            int r0 = (w * 4 + is) * 8;
            int row = r0 + lrow_off;
            int kg_log = kg_phys ^ (row & 7);
            gload_lds16(A + (size_t)(rowb + row) * K + k0 + kg_log * 8, &sA[r0 * BK]);
        }
#pragma unroll
        for (int is = 0; is < 2; ++is) {
            int r0 = (w * 2 + is) * 8;
            int row = r0 + lrow_off;
            int kg_log = kg_phys ^ (row & 7);
            gload_lds16(Bt + (size_t)(colb + row) * K + k0 + kg_log * 8, &sB[r0 * BK]);
        }
        asm volatile("s_waitcnt vmcnt(0)" ::: "memory");
        __syncthreads();

#pragma unroll
        for (int kk = 0; kk < BK; kk += 32) {
            int kg = (kk >> 3) + kgrp;
            bf16x8 af[4], bfv[2];
#pragma unroll
            for (int m = 0; m < 4; ++m) {
                int row = wr * 64 + m * 16 + fr;
                ushort8 raw = *(const ushort8*)&sA[row * BK + (kg ^ (row & 7)) * 8];
                af[m] = __builtin_bit_cast(bf16x8, raw);
            }
#pragma unroll
            for (int n = 0; n < 2; ++n) {
                int row = wc * 32 + n * 16 + fr;
                ushort8 raw = *(const ushort8*)&sB[row * BK + (kg ^ (row & 7)) * 8];
                bfv[n] = __builtin_bit_cast(bf16x8, raw);
            }
#pragma unroll
            for (int m = 0; m < 4; ++m)
#pragma unroll
                for (int n = 0; n < 2; ++n)
                    acc[m][n] = __builtin_amdgcn_mfma_f32_16x16x32_bf16(af[m], bfv[n], acc[m][n], 0, 0, 0);
        }
    }

#pragma unroll
    for (int m = 0; m < 4; ++m)
#pragma unroll
        for (int n = 0; n < 2; ++n) {
            int grow0 = rowb + wr * 64 + m * 16 + kgrp * 4;
            int gcol  = colb + wc * 32 + n * 16 + fr;
            float bv = bias ? bias[gcol] : 0.f;
#pragma unroll
            for (int r = 0; r < 4; ++r)
                C[(size_t)(grow0 + r) * N + gcol] = acc[m][n][r] + bv;
        }
}

// ------------------------------------------------------------------
// silu then L2-normalize per group of 64 with strided row layout.
// ------------------------------------------------------------------
__global__ void k_silu_norm(float* __restrict__ buf, int ngroups,
                            int gshift, int gmask, int rowstride, int coloff) {
    int w = threadIdx.x >> 6;
    int l = threadIdx.x & 63;
    int g = blockIdx.x * 4 + w;
    if (g >= ngroups) return;
    size_t idx = (size_t)(g >> gshift) * rowstride + coloff + ((g & gmask) << 6) + l;
    float x = buf[idx];
    float s = x / (1.f + expf(-x));
    float ss = s * s;
#pragma unroll
    for (int m = 1; m < 64; m <<= 1) ss += __shfl_xor(ss, m);
    float nrm = sqrtf(ss) + 1e-6f;
    buf[idx] = s / nrm;
}

// ------------------------------------------------------------------
// Phase 1: per (bh, chunk): transfer ops (A_c, B_c) AND per-token
// projected vectors a_s = A^pre_s q_s, b_s = B^pre_s q_s (-> ab).
// Flattened double-rank update: per token, 3 INDEPENDENT dots
// (St.k0, St.k1, St.q) + precomputed token-scalars k0.k1, k0.q, k1.q
// give both coefs and x via scalar algebra — one dot round instead
// of three sequential ones. Token-scalars computed in staging with an
// 8-lane DPP reduce.
// ------------------------------------------------------------------
__global__ __launch_bounds__(512) void k_chunk_transfer(
    const float* __restrict__ proj, const float* __restrict__ maskf,
    float* __restrict__ Ac, float* __restrict__ Bc, float* __restrict__ ab)
{
    int c = blockIdx.x;
    int bh = blockIdx.y;
    int b = bh >> 3, h = bh & 7;
    int t = threadIdx.x;
    int half = t >> 8;         // 0 = A-state, 1 = B-state
    int tt = t & 255;
    int i = tt >> 2, g = tt & 3;
    __shared__ float sK[CL][128];     // 32 KB
    __shared__ float sQ[CL][64];      // 16 KB
    __shared__ float4 sScal[CL];      // {b0, b1, maskscale, -}
    __shared__ float4 sDots[CL];      // {k0.k1, k0.q, k1.q, -}

    size_t tokbase = (size_t)(b * S_ + c * CL);
#pragma unroll
    for (int it = 0; it < (CL * 32) / 512; ++it) {
        int f = it * 512 + t;
        int tok = f >> 5, wi = f & 31;
        *(float4*)&sK[tok][wi * 4] = *(const float4*)&proj[(tokbase + tok) * NPROJ + KOFF + h * 128 + wi * 4];
    }
#pragma unroll
    for (int it = 0; it < (CL * 16) / 512; ++it) {
        int f = it * 512 + t;
        int tok = f >> 4, wi = f & 15;
        *(float4*)&sQ[tok][wi * 4] = *(const float4*)&proj[(tokbase + tok) * NPROJ + QOFF + h * 64 + wi * 4];
    }
    if (t < CL) {
        float r0 = proj[(tokbase + t) * NPROJ + BOFF + h * 2 + 0];
        float r1 = proj[(tokbase + t) * NPROJ + BOFF + h * 2 + 1];
        float ms = 1.f - maskf[tokbase + t];
        sScal[t] = make_float4(1.f / (1.f + expf(-r0)), 1.f / (1.f + expf(-r1)), ms, 0.f);
    }
    __syncthreads();

    // token-scalars: 8 threads per token, 8 elems each, DPP 8-lane reduce
    {
        int tok = t >> 3, sub = t & 7;
        int e0 = sub * 8;
        float p01 = 0.f, p0q = 0.f, p1q = 0.f;
#pragma unroll
        for (int e = 0; e < 8; ++e) {
            float k0e = sK[tok][e0 + e];
            float k1e = sK[tok][64 + e0 + e];
            float qe  = sQ[tok][e0 + e];
            p01 = fmaf(k0e, k1e, p01);
            p0q = fmaf(k0e, qe,  p0q);
            p1q = fmaf(k1e, qe,  p1q);
        }
        p01 = qsum8(p01); p0q = qsum8(p0q); p1q = qsum8(p1q);
        if (sub == 0) sDots[tok] = make_float4(p01, p0q, p1q, 0.f);
    }
    __syncthreads();

    float St[16];
#pragma unroll
    for (int jl = 0; jl < 16; ++jl)
        St[jl] = (half == 0 && g * 16 + jl == i) ? 1.f : 0.f;

    const float* vbase = &proj[tokbase * NPROJ + VOFF + h * 128];
    float v0 = 0.f, v1 = 0.f;
    if (half) { v0 = vbase[i]; v1 = vbase[64 + i]; }

    float* abdst = ab + ((size_t)bh * NC + c) * (size_t)(CL * 128) + half * 64 + i;

    for (int sl = 0; sl < CL; ++sl) {
        float vc0 = v0, vc1 = v1;
        if (half && sl + 1 < CL) {
            const float* nb = vbase + (size_t)(sl + 1) * NPROJ;
            v0 = nb[i]; v1 = nb[64 + i];
        }
        float4 sc = sScal[sl];
        float4 dt = sDots[sl];
        if (sc.z == 0.f) {           // masked token: state reset (block-uniform, ~5%)
#pragma unroll
            for (int jl = 0; jl < 16; ++jl) St[jl] = 0.f;
        }
        float k0[16], k1[16], qq[16];
        *(float4*)&k0[0]  = *(const float4*)&sK[sl][g * 16];
        *(float4*)&k0[4]  = *(const float4*)&sK[sl][g * 16 + 4];
        *(float4*)&k0[8]  = *(const float4*)&sK[sl][g * 16 + 8];
        *(float4*)&k0[12] = *(const float4*)&sK[sl][g * 16 + 12];
        *(float4*)&k1[0]  = *(const float4*)&sK[sl][64 + g * 16];
        *(float4*)&k1[4]  = *(const float4*)&sK[sl][64 + g * 16 + 4];
        *(float4*)&k1[8]  = *(const float4*)&sK[sl][64 + g * 16 + 8];
        *(float4*)&k1[12] = *(const float4*)&sK[sl][64 + g * 16 + 12];
        *(float4*)&qq[0]  = *(const float4*)&sQ[sl][g * 16];
        *(float4*)&qq[4]  = *(const float4*)&sQ[sl][g * 16 + 4];
        *(float4*)&qq[8]  = *(const float4*)&sQ[sl][g * 16 + 8];
        *(float4*)&qq[12] = *(const float4*)&sQ[sl][g * 16 + 12];
        // 3 independent dots, 4-way split each (12 parallel FMA chains)
        float a0 = 0.f, a1 = 0.f, a2 = 0.f, a3 = 0.f;
        float b0 = 0.f, b1 = 0.f, b2 = 0.f, b3 = 0.f;
        float c0v = 0.f, c1v = 0.f, c2v = 0.f, c3v = 0.f;
#pragma unroll
        for (int q = 0; q < 4; ++q) {
            a0 = fmaf(St[q],      k0[q],      a0);
            a1 = fmaf(St[4 + q],  k0[4 + q],  a1);
            a2 = fmaf(St[8 + q],  k0[8 + q],  a2);
            a3 = fmaf(St[12 + q], k0[12 + q], a3);
            b0 = fmaf(St[q],      k1[q],      b0);
            b1 = fmaf(St[4 + q],  k1[4 + q],  b1);
            b2 = fmaf(St[8 + q],  k1[8 + q],  b2);
            b3 = fmaf(St[12 + q], k1[12 + q], b3);
            c0v = fmaf(St[q],      qq[q],      c0v);
            c1v = fmaf(St[4 + q],  qq[4 + q],  c1v);
            c2v = fmaf(St[8 + q],  qq[8 + q],  c2v);
            c3v = fmaf(St[12 + q], qq[12 + q], c3v);
        }
        float d0 = qsum4((a0 + a1) + (a2 + a3));
        float d1 = qsum4((b0 + b1) + (b2 + b3));
        float dq = qsum4((c0v + c1v) + (c2v + c3v));
        // scalar algebra: both coefs without re-dotting
        float c0, c1;
        if (half == 0) {
            c0 = -sc.x * d0;
            float u1 = fmaf(c0, dt.x, d1);
            c1 = -sc.y * u1;
        } else {
            c0 = sc.x * (vc0 - d0);
            float u1 = fmaf(c0, dt.x, d1);
            c1 = sc.y * (vc1 - u1);
        }
        float xv = fmaf(c1, dt.z, fmaf(c0, dt.y, dq));
        if (g == 0) abdst[sl * 128] = xv;
#pragma unroll
        for (int jl = 0; jl < 16; ++jl) {
            St[jl] = fmaf(c0, k0[jl], St[jl]);
            St[jl] = fmaf(c1, k1[jl], St[jl]);
        }
    }
    float* dst = (half == 0 ? Ac : Bc) + ((size_t)bh * NC + c) * 4096 + (size_t)i * 64 + g * 16;
#pragma unroll
    for (int q4 = 0; q4 < 4; ++q4)
        *(float4*)&dst[q4 * 4] = *(float4*)&St[q4 * 4];
}

// ------------------------------------------------------------------
// Phase 2: sequential chunk combine, 64 blocks = 16 bh x 4 row-groups
// of 16 rows, NC=16 steps. Async LDS double-buffer for A; Bc
// register-prefetched one step ahead; padded state rows; separate S0.
// ------------------------------------------------------------------
__global__ __launch_bounds__(256) void k_combine(
    const float* __restrict__ Ac, const float* __restrict__ Bc,
    const float* __restrict__ carry, float* __restrict__ S0,
    float* __restrict__ carry_out)
{
    constexpr int SP = 68;
    int blk = blockIdx.x;
    int bh = blk >> 2, rg = blk & 3;
    int t = threadIdx.x;
    int i = t >> 4;
    int j0 = (t & 15) * 4;
    int gi = rg * 16 + i;
    __shared__ float sA[2][64 * 64];
    __shared__ float sS[16 * SP];

    size_t cb0 = (size_t)bh * NC * 4096;
#pragma unroll
    for (int s = 0; s < 4; ++s)
        gload_lds16(Ac + cb0 + (size_t)(s * 256 + t) * 4, &sA[0][(size_t)(s * 256 + (t & 192)) * 4]);
    float4 rB = *(const float4*)&Bc[cb0 + (size_t)gi * 64 + j0];
    float4 racc = *(const float4*)&carry[(size_t)bh * 4096 + (size_t)gi * 64 + j0];
    *(float4*)&sS[i * SP + j0] = racc;
    asm volatile("s_waitcnt vmcnt(0)" ::: "memory");
    __syncthreads();

    for (int c = 0; c < NC; ++c) {
        int cur = c & 1;
        size_t cb = cb0 + (size_t)c * 4096;
        float4 rBn;
        if (c + 1 < NC) {
#pragma unroll
            for (int s = 0; s < 4; ++s)
                gload_lds16(Ac + cb + 4096 + (size_t)(s * 256 + t) * 4,
                            &sA[cur ^ 1][(size_t)(s * 256 + (t & 192)) * 4]);
            rBn = *(const float4*)&Bc[cb + 4096 + (size_t)gi * 64 + j0];
        }
        *(float4*)&S0[cb + (size_t)gi * 64 + j0] = racc;
        float4 acc = rB;
        float4 ac2 = make_float4(0.f, 0.f, 0.f, 0.f);
#pragma unroll
        for (int p4 = 0; p4 < 16; p4 += 2) {
            float4 s0v = *(const float4*)&sS[i * SP + p4 * 4];
            float4 s1v = *(const float4*)&sS[i * SP + p4 * 4 + 4];
            float4 a0 = *(const float4*)&sA[cur][(p4 * 4 + 0) * 64 + j0];
            float4 a1 = *(const float4*)&sA[cur][(p4 * 4 + 1) * 64 + j0];
            float4 a2 = *(const float4*)&sA[cur][(p4 * 4 + 2) * 64 + j0];
            float4 a3 = *(const float4*)&sA[cur][(p4 * 4 + 3) * 64 + j0];
            float4 a4 = *(const float4*)&sA[cur][(p4 * 4 + 4) * 64 + j0];
            float4 a5 = *(const float4*)&sA[cur][(p4 * 4 + 5) * 64 + j0];
            float4 a6 = *(const float4*)&sA[cur][(p4 * 4 + 6) * 64 + j0];
            float4 a7 = *(const float4*)&sA[cur][(p4 * 4 + 7) * 64 + j0];
            acc.x = fmaf(s0v.x, a0.x, acc.x); acc.y = fmaf(s0v.x, a0.y, acc.y);
            acc.z = fmaf(s0v.x, a0.z, acc.z); acc.w = fmaf(s0v.x, a0.w, acc.w);
            ac2.x = fmaf(s0v.y, a1.x, ac2.x); ac2.y = fmaf(s0v.y, a1.y, ac2.y);
            ac2.z = fmaf(s0v.y, a1.z, ac2.z); ac2.w = fmaf(s0v.y, a1.w, ac2.w);
            acc.x = fmaf(s0v.z, a2.x, acc.x); acc.y = fmaf(s0v.z, a2.y, acc.y);
            acc.z = fmaf(s0v.z, a2.z, acc.z); acc.w = fmaf(s0v.z, a2.w, acc.w);
            ac2.x = fmaf(s0v.w, a3.x, ac2.x); ac2.y = fmaf(s0v.w, a3.y, ac2.y);
            ac2.z = fmaf(s0v.w, a3.z, ac2.z); ac2.w = fmaf(s0v.w, a3.w, ac2.w);
            acc.x = fmaf(s1v.x, a4.x, acc.x); acc.y = fmaf(s1v.x, a4.y, acc.y);
            acc.z = fmaf(s1v.x, a4.z, acc.z); acc.w = fmaf(s1v.x, a4.w, acc.w);
            ac2.x = fmaf(s1v.y, a5.x, ac2.x); ac2.y = fmaf(s1v.y, a5.y, ac2.y);
            ac2.z = fmaf(s1v.y, a5.z, ac2.z); ac2.w = fmaf(s1v.y, a5.w, ac2.w);
            acc.x = fmaf(s1v.z, a6.x, acc.x); acc.y = fmaf(s1v.z, a6.y, acc.y);
            acc.z = fmaf(s1v.z, a6.z, acc.z); acc.w = fmaf(s1v.z, a6.w, acc.w);
            ac2.x = fmaf(s1v.w, a7.x, ac2.x); ac2.y = fmaf(s1v.w, a7.y, ac2.y);
            ac2.z = fmaf(s1v.w, a7.z, ac2.z); ac2.w = fmaf(s1v.w, a7.w, ac2.w);
        }
        acc.x += ac2.x; acc.y += ac2.y; acc.z += ac2.z; acc.w += ac2.w;
        __syncthreads();
        *(float4*)&sS[i * SP + j0] = acc;
        racc = acc;
        rB = rBn;
        asm volatile("s_waitcnt vmcnt(0)" ::: "memory");
        __syncthreads();
    }
    *(float4*)&carry_out[(size_t)bh * 4096 + (size_t)gi * 64 + j0] = racc;
}

// ------------------------------------------------------------------
// Phase 3: X_chunk = Aa @ S0^T + Bb  per (bh, chunk).
// ab[(bh,c)][s][half][i]: half 0 = a_s, half 1 = b_s.
// ------------------------------------------------------------------
__global__ __launch_bounds__(256) void k_xgemm(
    const float* __restrict__ ab, const float* __restrict__ S0,
    float* __restrict__ proj)
{
    constexpr int P = 67;
    int c = blockIdx.x, bh = blockIdx.y;
    int b = bh >> 3, h = bh & 7;
    int t = threadIdx.x;
    __shared__ float sAaT[64 * P];   // Aa^T : [p][s]
    __shared__ float sS0T[64 * P];   // S0^T : [p][i]
    size_t abbase = ((size_t)bh * NC + c) * (size_t)(CL * 128);
    size_t s0base = ((size_t)bh * NC + c) * 4096;

#pragma unroll
    for (int it = 0; it < 4; ++it) {
        int f = it * 256 + t;
        int r = f >> 4, p0 = (f & 15) * 4;
        float4 va = *(const float4*)&ab[abbase + (size_t)r * 128 + p0];
        sAaT[(p0 + 0) * P + r] = va.x; sAaT[(p0 + 1) * P + r] = va.y;
        sAaT[(p0 + 2) * P + r] = va.z; sAaT[(p0 + 3) * P + r] = va.w;
        float4 vs = *(const float4*)&S0[s0base + (size_t)r * 64 + p0];
        sS0T[(p0 + 0) * P + r] = vs.x; sS0T[(p0 + 1) * P + r] = vs.y;
        sS0T[(p0 + 2) * P + r] = vs.z; sS0T[(p0 + 3) * P + r] = vs.w;
    }
    __syncthreads();

    int s0r = (t >> 4) * 4;
    int i0 = (t & 15) * 4;
    size_t tokbase = (size_t)(b * S_ + c * CL);
    float4 acc[4];
#pragma unroll
    for (int a = 0; a < 4; ++a)
        acc[a] = *(const float4*)&ab[abbase + (size_t)(s0r + a) * 128 + 64 + i0];
#pragma unroll 8
    for (int p = 0; p < 64; ++p) {
        float4 aa = *(const float4*)&sAaT[p * P + s0r];
        float4 ss = *(const float4*)&sS0T[p * P + i0];
        acc[0].x = fmaf(aa.x, ss.x, acc[0].x); acc[0].y = fmaf(aa.x, ss.y, acc[0].y);
        acc[0].z = fmaf(aa.x, ss.z, acc[0].z); acc[0].w = fmaf(aa.x, ss.w, acc[0].w);
        acc[1].x = fmaf(aa.y, ss.x, acc[1].x); acc[1].y = fmaf(aa.y, ss.y, acc[1].y);
        acc[1].z = fmaf(aa.y, ss.z, acc[1].z); acc[1].w = fmaf(aa.y, ss.w, acc[1].w);
        acc[2].x = fmaf(aa.z, ss.x, acc[2].x); acc[2].y = fmaf(aa.z, ss.y, acc[2].y);
        acc[2].z = fmaf(aa.z, ss.z, acc[2].z); acc[2].w = fmaf(aa.z, ss.w, acc[2].w);
        acc[3].x = fmaf(aa.w, ss.x, acc[3].x); acc[3].y = fmaf(aa.w, ss.y, acc[3].y);
        acc[3].z = fmaf(aa.w, ss.z, acc[3].z); acc[3].w = fmaf(aa.w, ss.w, acc[3].w);
    }
#pragma unroll
    for (int a = 0; a < 4; ++a)
        *(float4*)&proj[(tokbase + s0r + a) * NPROJ + QOFF + h * 64 + i0] = acc[a];
}

// ------------------------------------------------------------------
// RMS norm over x = proj cols 0..511, * rms_scale, emit compact bf16.
// ------------------------------------------------------------------
__global__ void k_rms_bf16(const float* __restrict__ proj, const float* __restrict__ scale,
                           unsigned short* __restrict__ xo) {
    int w = threadIdx.x >> 6;
    int l = threadIdx.x & 63;
    size_t row = (size_t)blockIdx.x * 4 + w;
    float4 v0 = *(const float4*)&proj[row * NPROJ + l * 8];
    float4 v1 = *(const float4*)&proj[row * NPROJ + l * 8 + 4];
    float ss = v0.x * v0.x + v0.y * v0.y + v0.z * v0.z + v0.w * v0.w
             + v1.x * v1.x + v1.y * v1.y + v1.z * v1.z + v1.w * v1.w;
#pragma unroll
    for (int m = 1; m < 64; m <<= 1) ss += __shfl_xor(ss, m);
    float sc = rsqrtf(ss * (1.f / 512.f) + 1e-6f);
    float4 s0 = *(const float4*)&scale[l * 8];
    float4 s1 = *(const float4*)&scale[l * 8 + 4];
    ushort8 o;
    o[0] = f2bf(v0.x * sc * s0.x); o[1] = f2bf(v0.y * sc * s0.y);
    o[2] = f2bf(v0.z * sc * s0.z); o[3] = f2bf(v0.w * sc * s0.w);
    o[4] = f2bf(v1.x * sc * s1.x); o[5] = f2bf(v1.y * sc * s1.y);
    o[6] = f2bf(v1.z * sc * s1.z); o[7] = f2bf(v1.w * sc * s1.w);
    *(ushort8*)&xo[row * 512 + l * 8] = o;
}

// ------------------------------------------------------------------
extern "C" void kernel_launch(void* const* d_in, const int* in_sizes, int n_in,
                              void* d_out, int out_size, void* d_ws, size_t ws_size,
                              hipStream_t stream) {
    const float* inputs    = (const float*)d_in[0];
    const void*  mask      = d_in[1];
    const float* carry     = (const float*)d_in[2];
    const float* Wq        = (const float*)d_in[3];
    const float* Wk        = (const float*)d_in[4];
    const float* Wv        = (const float*)d_in[5];
    const float* Wb        = (const float*)d_in[6];
    const float* rms_scale = (const float*)d_in[7];
    const float* Wo        = (const float*)d_in[8];
    const float* bo        = (const float*)d_in[9];

    float* out_carry = (float*)d_out;
    float* out_y     = (float*)d_out + (size_t)B_ * H_ * D_ * D_;

    const int M = B_ * S_;  // 2048
    float* ws = (float*)d_ws;
    size_t o = 0;
    float* proj = ws + o; o += (size_t)M * NPROJ;            // 5.37M f
    float* mf   = ws + o; o += (size_t)M;
    float* Ac   = ws + o; o += (size_t)BH * NC * 4096;       // 1M f
    float* Bc   = ws + o; o += (size_t)BH * NC * 4096;       // 1M f
    float* S0   = ws + o; o += (size_t)BH * NC * 4096;       // 1M f
    float* abuf = ws + o; o += (size_t)BH * NC * CL * 128;   // 2M f
    unsigned short* wt = (unsigned short*)(ws + o); o += (size_t)NPROJ * 512;
    // overlays (lifetimes disjoint):
    unsigned short* inb = (unsigned short*)Bc;   // bf16 inputs, dead before transfer writes Bc
    unsigned short* xbf = (unsigned short*)Ac;   // rms output; Ac dead after combine

    k_mask_prep<<<1, 256, 0, stream>>>(mask, mf, M);
    k_f32_to_bf16<<<(M * 1024) / 1024, 256, 0, stream>>>(inputs, inb, M * 1024);

    // pack W^T = [Wq^T | Wk^T | Wv^T | Wb^T(pad to 64)] as [NPROJ,1024] bf16
    k_transpose_to_bf16<<<dim3(512 / 32, 1024 / 32), 256, 0, stream>>>(Wq, wt + (size_t)QOFF * 1024, 1024, 512);
    k_transpose_to_bf16<<<dim3(1024 / 32, 1024 / 32), 256, 0, stream>>>(Wk, wt + (size_t)KOFF * 1024, 1024, 1024);
    k_transpose_to_bf16<<<dim3(1024 / 32, 1024 / 32), 256, 0, stream>>>(Wv, wt + (size_t)VOFF * 1024, 1024, 1024);
    k_wb_pad<<<64, 256, 0, stream>>>(Wb, wt + (size_t)BOFF * 1024);

    // proj = inputs @ [Wq|Wk|Wv|Wb]
    k_gemm_bf16<<<dim3(NPROJ / 64, M / 128), 256, 0, stream>>>(inb, wt, nullptr, proj, M, NPROJ, 1024);

    // silu+L2norm on q (8 groups/row) and k (16 groups/row)
    k_silu_norm<<<(M * 8) / 4, 256, 0, stream>>>(proj, M * 8, 3, 7, NPROJ, QOFF);
    k_silu_norm<<<(M * 16) / 4, 256, 0, stream>>>(proj, M * 16, 4, 15, NPROJ, KOFF);

    // scan: transfer (+ per-token a,b vectors) -> combine -> X = Aa@S0^T + Bb
    k_chunk_transfer<<<dim3(NC, BH), 512, 0, stream>>>(proj, mf, Ac, Bc, abuf);
    k_combine<<<BH * 4, 256, 0, stream>>>(Ac, Bc, carry, S0, out_carry);
    k_xgemm<<<dim3(NC, BH), 256, 0, stream>>>(abuf, S0, proj);

    k_rms_bf16<<<M / 4, 256, 0, stream>>>(proj, rms_scale, xbf);

    // y = x @ Wo + bo  (K=512, N=1024); reuse wt for Wo^T
    k_transpose_to_bf16<<<dim3(1024 / 32, 512 / 32), 256, 0, stream>>>(Wo, wt, 512, 1024);
    k_gemm_bf16<<<dim3(1024 / 64, M / 128), 256, 0, stream>>>(xbf, wt, bo, out_y, M, 1024, 512);
}